// Round 1
// baseline (2083.424 us; speedup 1.0000x reference)
//
#include <hip/hip_runtime.h>
#include <math.h>

#define NN   40000
#define EE   640000
#define ETOT (EE + NN)          // 680000 edges incl self-loops
#define NBLK ((NN + 255) / 256) // 157

// ---------------------------------------------------------------- CSR build
__global__ void count_k(const int* __restrict__ ei, int* __restrict__ counts) {
    int e = blockIdx.x * 256 + threadIdx.x;
    if (e >= ETOT) return;
    int d = (e < EE) ? ei[EE + e] : (e - EE);
    atomicAdd(&counts[d], 1);
}

__global__ __launch_bounds__(256) void scan_k(const int* __restrict__ in,
                                              int* __restrict__ out,
                                              int* __restrict__ sums, int n) {
    __shared__ int tmp[256];
    int i = blockIdx.x * 256 + threadIdx.x;
    int v = (i < n) ? in[i] : 0;
    tmp[threadIdx.x] = v;
    __syncthreads();
    #pragma unroll
    for (int off = 1; off < 256; off <<= 1) {
        int t = (threadIdx.x >= off) ? tmp[threadIdx.x - off] : 0;
        __syncthreads();
        tmp[threadIdx.x] += t;
        __syncthreads();
    }
    if (i < n) out[i] = tmp[threadIdx.x] - v;   // exclusive
    if (sums != nullptr && threadIdx.x == 255) sums[blockIdx.x] = tmp[255];
}

__global__ void add_off_k(int* __restrict__ data, const int* __restrict__ offs) {
    int i = blockIdx.x * 256 + threadIdx.x;
    if (i < NN) data[i] += offs[blockIdx.x];
    if (blockIdx.x == 0 && threadIdx.x == 0) data[NN] = ETOT;
}

__global__ void scatter_k(const int* __restrict__ ei, const int* __restrict__ rowptr,
                          int* __restrict__ cursor, int* __restrict__ csr_src) {
    int e = blockIdx.x * 256 + threadIdx.x;
    if (e >= ETOT) return;
    int s, d;
    if (e < EE) { s = ei[e]; d = ei[EE + e]; } else { s = d = e - EE; }
    int pos = rowptr[d] + atomicAdd(&cursor[d], 1);
    csr_src[pos] = s;
}

// ---------------------------------------------------------------- GEMM
// C[M,N] = A[M,K] @ B[K,N]   (MODE 0: write; 1: C=elu(C+AB+bias); 2: C=C+AB+bias)
template <int MODE>
__global__ __launch_bounds__(256) void gemm_k(const float* __restrict__ A,
                                              const float* __restrict__ B,
                                              const float* __restrict__ bias,
                                              float* __restrict__ C,
                                              int M, int N, int K) {
    __shared__ float As[16][64];
    __shared__ float Bs[16][64];
    int bm = blockIdx.y * 64;
    int bn = blockIdx.x * 64;
    int tid = threadIdx.x;
    int tx = tid & 15, ty = tid >> 4;
    float acc[4][4] = {};
    for (int k0 = 0; k0 < K; k0 += 16) {
        #pragma unroll
        for (int i = 0; i < 4; ++i) {
            int idx = tid + i * 256;
            int r = idx >> 4, kk = idx & 15;
            int gr = bm + r, gk = k0 + kk;
            As[kk][r] = (gr < M && gk < K) ? A[(size_t)gr * K + gk] : 0.f;
        }
        #pragma unroll
        for (int i = 0; i < 4; ++i) {
            int idx = tid + i * 256;
            int r = idx >> 6, c = idx & 63;
            int gk = k0 + r, gc = bn + c;
            Bs[r][c] = (gk < K && gc < N) ? B[(size_t)gk * N + gc] : 0.f;
        }
        __syncthreads();
        #pragma unroll
        for (int kk = 0; kk < 16; ++kk) {
            float a[4], b[4];
            #pragma unroll
            for (int i = 0; i < 4; ++i) a[i] = As[kk][ty * 4 + i];
            #pragma unroll
            for (int j = 0; j < 4; ++j) b[j] = Bs[kk][tx * 4 + j];
            #pragma unroll
            for (int i = 0; i < 4; ++i)
                #pragma unroll
                for (int j = 0; j < 4; ++j) acc[i][j] += a[i] * b[j];
        }
        __syncthreads();
    }
    #pragma unroll
    for (int i = 0; i < 4; ++i) {
        int gr = bm + ty * 4 + i;
        if (gr >= M) continue;
        #pragma unroll
        for (int j = 0; j < 4; ++j) {
            int gc = bn + tx * 4 + j;
            if (gc >= N) continue;
            size_t o = (size_t)gr * N + gc;
            float v = acc[i][j];
            if (MODE == 0) {
                C[o] = v;
            } else {
                float w = C[o] + v + bias[gc];
                if (MODE == 1) w = (w > 0.f) ? w : expm1f(w);
                C[o] = w;
            }
        }
    }
}

// ---------------------------------------------------------------- attention coeffs
// al[n,h] = dot(hfeat[n, h*OC:(h+1)*OC], att_src[h]); same for ar with att_dst
__global__ __launch_bounds__(64) void alar_k(const float* __restrict__ hfeat,
                                             const float* __restrict__ att_src,
                                             const float* __restrict__ att_dst,
                                             float* __restrict__ al, float* __restrict__ ar,
                                             int H, int OC) {
    int h = blockIdx.x;
    int n = blockIdx.y;
    int lane = threadIdx.x;
    const float* hp = hfeat + (size_t)n * H * OC + h * OC;
    float a = 0.f, b = 0.f;
    for (int c = lane; c < OC; c += 64) {
        float v = hp[c];
        a += v * att_src[h * OC + c];
        b += v * att_dst[h * OC + c];
    }
    #pragma unroll
    for (int off = 32; off > 0; off >>= 1) {
        a += __shfl_down(a, off);
        b += __shfl_down(b, off);
    }
    if (lane == 0) { al[n * H + h] = a; ar[n * H + h] = b; }
}

// ---------------------------------------------------------------- gather (concat, H=4, OC=64)
__global__ __launch_bounds__(256) void gather_concat_k(const int* __restrict__ rowptr,
                                                       const int* __restrict__ csr_src,
                                                       const float* __restrict__ hfeat,
                                                       const float* __restrict__ al,
                                                       const float* __restrict__ ar,
                                                       const float* __restrict__ bias,
                                                       float* __restrict__ out) {
    int n = blockIdx.x;
    int tid = threadIdx.x;
    int head = tid >> 6;
    int beg = rowptr[n], end = rowptr[n + 1];
    float ard = ar[n * 4 + head];
    float m = -1e30f, s = 0.f, acc = 0.f;
    for (int e = beg; e < end; ++e) {
        int src = csr_src[e];
        float lg = al[src * 4 + head] + ard;
        lg = (lg > 0.f) ? lg : 0.2f * lg;
        float hv = hfeat[(size_t)src * 256 + tid];
        float mn = fmaxf(m, lg);
        float sc = expf(m - mn);
        float p  = expf(lg - mn);
        s   = s * sc + p;
        acc = acc * sc + p * hv;
        m = mn;
    }
    out[(size_t)n * 256 + tid] = acc / s + bias[tid];
}

// ---------------------------------------------------------------- gather (mean, H=6, OC=121)
__global__ __launch_bounds__(768) void gather_mean_k(const int* __restrict__ rowptr,
                                                     const int* __restrict__ csr_src,
                                                     const float* __restrict__ hfeat,
                                                     const float* __restrict__ al,
                                                     const float* __restrict__ ar,
                                                     const float* __restrict__ bias,
                                                     float* __restrict__ out) {
    __shared__ float red[6 * 128];
    int n = blockIdx.x;
    int tid = threadIdx.x;
    int head = tid >> 7;        // 0..5
    int c = tid & 127;
    bool active = (c < 121);
    int beg = rowptr[n], end = rowptr[n + 1];
    float ard = ar[n * 6 + head];
    float m = -1e30f, s = 0.f, acc = 0.f;
    for (int e = beg; e < end; ++e) {
        int src = csr_src[e];
        float lg = al[src * 6 + head] + ard;
        lg = (lg > 0.f) ? lg : 0.2f * lg;
        float hv = active ? hfeat[(size_t)src * 726 + head * 121 + c] : 0.f;
        float mn = fmaxf(m, lg);
        float sc = expf(m - mn);
        float p  = expf(lg - mn);
        s   = s * sc + p;
        acc = acc * sc + p * hv;
        m = mn;
    }
    red[head * 128 + c] = acc / s;
    __syncthreads();
    if (head == 0 && active) {
        float t = 0.f;
        #pragma unroll
        for (int h2 = 0; h2 < 6; ++h2) t += red[h2 * 128 + c];
        out[(size_t)n * 121 + c] = t * (1.f / 6.f) + bias[c];
    }
}

// ---------------------------------------------------------------- launch
extern "C" void kernel_launch(void* const* d_in, const int* in_sizes, int n_in,
                              void* d_out, int out_size, void* d_ws, size_t ws_size,
                              hipStream_t stream) {
    const float* x   = (const float*)d_in[0];
    const int*   ei  = (const int*)d_in[1];
    const float* W1  = (const float*)d_in[2];
    const float* a1s = (const float*)d_in[3];
    const float* a1d = (const float*)d_in[4];
    const float* b1  = (const float*)d_in[5];
    const float* Wl1 = (const float*)d_in[6];
    const float* bl1 = (const float*)d_in[7];
    const float* W2  = (const float*)d_in[8];
    const float* a2s = (const float*)d_in[9];
    const float* a2d = (const float*)d_in[10];
    const float* b2  = (const float*)d_in[11];
    const float* Wl2 = (const float*)d_in[12];
    const float* bl2 = (const float*)d_in[13];
    const float* W3  = (const float*)d_in[14];
    const float* a3s = (const float*)d_in[15];
    const float* a3d = (const float*)d_in[16];
    const float* b3  = (const float*)d_in[17];
    const float* Wl3 = (const float*)d_in[18];
    const float* bl3 = (const float*)d_in[19];

    float* out    = (float*)d_out;                 // [40000,121]
    float* hidden = out + (size_t)NN * 121;        // [40000,256]

    // workspace layout
    char* ws = (char*)d_ws;
    size_t off = 0;
    auto alloc = [&](size_t bytes) { size_t o = off; off = (off + bytes + 255) & ~(size_t)255; return o; };
    int*   counts    = (int*)(ws + alloc((size_t)NN * 4));
    int*   rowptr    = (int*)(ws + alloc((size_t)(NN + 1) * 4));
    int*   blocksums = (int*)(ws + alloc(256 * 4));
    int*   csr_src   = (int*)(ws + alloc((size_t)ETOT * 4));
    float* al        = (float*)(ws + alloc((size_t)NN * 6 * 4));
    float* ar        = (float*)(ws + alloc((size_t)NN * 6 * 4));
    float* hfeat     = (float*)(ws + alloc((size_t)NN * 726 * 4));
    float* h1        = (float*)(ws + alloc((size_t)NN * 256 * 4));

    const int eblocks = (ETOT + 255) / 256;

    // ---- CSR build (same for all layers)
    hipMemsetAsync(counts, 0, (size_t)NN * 4, stream);
    count_k<<<eblocks, 256, 0, stream>>>(ei, counts);
    scan_k<<<NBLK, 256, 0, stream>>>(counts, rowptr, blocksums, NN);
    scan_k<<<1, 256, 0, stream>>>(blocksums, blocksums, nullptr, NBLK);
    add_off_k<<<NBLK, 256, 0, stream>>>(rowptr, blocksums);
    hipMemsetAsync(counts, 0, (size_t)NN * 4, stream);  // reuse as cursor
    scatter_k<<<eblocks, 256, 0, stream>>>(ei, rowptr, counts, csr_src);

    // ---- Layer 1: in=x[N,50], out=h1[N,256]
    gemm_k<0><<<dim3(4, NN / 64), 256, 0, stream>>>(x, W1, nullptr, hfeat, NN, 256, 50);
    alar_k<<<dim3(4, NN), 64, 0, stream>>>(hfeat, a1s, a1d, al, ar, 4, 64);
    gather_concat_k<<<NN, 256, 0, stream>>>(rowptr, csr_src, hfeat, al, ar, b1, h1);
    gemm_k<1><<<dim3(4, NN / 64), 256, 0, stream>>>(x, Wl1, bl1, h1, NN, 256, 50);

    // ---- Layer 2: in=h1[N,256], out=hidden[N,256] (d_out)
    gemm_k<0><<<dim3(4, NN / 64), 256, 0, stream>>>(h1, W2, nullptr, hfeat, NN, 256, 256);
    alar_k<<<dim3(4, NN), 64, 0, stream>>>(hfeat, a2s, a2d, al, ar, 4, 64);
    gather_concat_k<<<NN, 256, 0, stream>>>(rowptr, csr_src, hfeat, al, ar, b2, hidden);
    gemm_k<1><<<dim3(4, NN / 64), 256, 0, stream>>>(h1, Wl2, bl2, hidden, NN, 256, 256);

    // ---- Layer 3: in=hidden[N,256], out=out[N,121] (mean over 6 heads)
    gemm_k<0><<<dim3(12, NN / 64), 256, 0, stream>>>(hidden, W3, nullptr, hfeat, NN, 726, 256);
    alar_k<<<dim3(6, NN), 64, 0, stream>>>(hfeat, a3s, a3d, al, ar, 6, 121);
    gather_mean_k<<<NN, 768, 0, stream>>>(rowptr, csr_src, hfeat, al, ar, b3, out);
    gemm_k<2><<<dim3(2, NN / 64), 256, 0, stream>>>(hidden, Wl3, bl3, out, NN, 121, 256);
}

// Round 2
// 1570.435 us; speedup vs baseline: 1.3267x; 1.3267x over previous
//
#include <hip/hip_runtime.h>
#include <math.h>

#define NN   40000
#define EE   640000
#define ETOT (EE + NN)          // 680000 edges incl self-loops
#define NBLK ((NN + 255) / 256) // 157

// ---------------------------------------------------------------- CSR build
__global__ void count_k(const int* __restrict__ ei, int* __restrict__ counts) {
    int e = blockIdx.x * 256 + threadIdx.x;
    if (e >= ETOT) return;
    int d = (e < EE) ? ei[EE + e] : (e - EE);
    atomicAdd(&counts[d], 1);
}

__global__ __launch_bounds__(256) void scan_k(const int* __restrict__ in,
                                              int* __restrict__ out,
                                              int* __restrict__ sums, int n) {
    __shared__ int tmp[256];
    int i = blockIdx.x * 256 + threadIdx.x;
    int v = (i < n) ? in[i] : 0;
    tmp[threadIdx.x] = v;
    __syncthreads();
    #pragma unroll
    for (int off = 1; off < 256; off <<= 1) {
        int t = (threadIdx.x >= off) ? tmp[threadIdx.x - off] : 0;
        __syncthreads();
        tmp[threadIdx.x] += t;
        __syncthreads();
    }
    if (i < n) out[i] = tmp[threadIdx.x] - v;   // exclusive
    if (sums != nullptr && threadIdx.x == 255) sums[blockIdx.x] = tmp[255];
}

__global__ void add_off_k(int* __restrict__ data, const int* __restrict__ offs) {
    int i = blockIdx.x * 256 + threadIdx.x;
    if (i < NN) data[i] += offs[blockIdx.x];
    if (blockIdx.x == 0 && threadIdx.x == 0) data[NN] = ETOT;
}

__global__ void scatter_k(const int* __restrict__ ei, const int* __restrict__ rowptr,
                          int* __restrict__ cursor, int* __restrict__ csr_src) {
    int e = blockIdx.x * 256 + threadIdx.x;
    if (e >= ETOT) return;
    int s, d;
    if (e < EE) { s = ei[e]; d = ei[EE + e]; } else { s = d = e - EE; }
    int pos = rowptr[d] + atomicAdd(&cursor[d], 1);
    csr_src[pos] = s;
}

// ---------------------------------------------------------------- GEMM
// C[M,N] = A[M,K] @ B[K,N]   (MODE 0: write; 1: C=elu(C+AB+bias); 2: C=C+AB+bias)
template <int MODE>
__global__ __launch_bounds__(256) void gemm_k(const float* __restrict__ A,
                                              const float* __restrict__ B,
                                              const float* __restrict__ bias,
                                              float* __restrict__ C,
                                              int M, int N, int K) {
    __shared__ float As[16][64];
    __shared__ float Bs[16][64];
    int bm = blockIdx.y * 64;
    int bn = blockIdx.x * 64;
    int tid = threadIdx.x;
    int tx = tid & 15, ty = tid >> 4;
    float acc[4][4] = {};
    for (int k0 = 0; k0 < K; k0 += 16) {
        #pragma unroll
        for (int i = 0; i < 4; ++i) {
            int idx = tid + i * 256;
            int r = idx >> 4, kk = idx & 15;
            int gr = bm + r, gk = k0 + kk;
            As[kk][r] = (gr < M && gk < K) ? A[(size_t)gr * K + gk] : 0.f;
        }
        #pragma unroll
        for (int i = 0; i < 4; ++i) {
            int idx = tid + i * 256;
            int r = idx >> 6, c = idx & 63;
            int gk = k0 + r, gc = bn + c;
            Bs[r][c] = (gk < K && gc < N) ? B[(size_t)gk * N + gc] : 0.f;
        }
        __syncthreads();
        #pragma unroll
        for (int kk = 0; kk < 16; ++kk) {
            float a[4], b[4];
            #pragma unroll
            for (int i = 0; i < 4; ++i) a[i] = As[kk][ty * 4 + i];
            #pragma unroll
            for (int j = 0; j < 4; ++j) b[j] = Bs[kk][tx * 4 + j];
            #pragma unroll
            for (int i = 0; i < 4; ++i)
                #pragma unroll
                for (int j = 0; j < 4; ++j) acc[i][j] += a[i] * b[j];
        }
        __syncthreads();
    }
    #pragma unroll
    for (int i = 0; i < 4; ++i) {
        int gr = bm + ty * 4 + i;
        if (gr >= M) continue;
        #pragma unroll
        for (int j = 0; j < 4; ++j) {
            int gc = bn + tx * 4 + j;
            if (gc >= N) continue;
            size_t o = (size_t)gr * N + gc;
            float v = acc[i][j];
            if (MODE == 0) {
                C[o] = v;
            } else {
                float w = C[o] + v + bias[gc];
                if (MODE == 1) w = (w > 0.f) ? w : expm1f(w);
                C[o] = w;
            }
        }
    }
}

// ---------------------------------------------------------------- attention coeffs
// al[n,h] = dot(hfeat[n, h*OC:(h+1)*OC], att_src[h]); same for ar with att_dst
__global__ __launch_bounds__(64) void alar_k(const float* __restrict__ hfeat,
                                             const float* __restrict__ att_src,
                                             const float* __restrict__ att_dst,
                                             float* __restrict__ al, float* __restrict__ ar,
                                             int H, int OC) {
    int h = blockIdx.x;
    int n = blockIdx.y;
    int lane = threadIdx.x;
    const float* hp = hfeat + (size_t)n * H * OC + h * OC;
    float a = 0.f, b = 0.f;
    for (int c = lane; c < OC; c += 64) {
        float v = hp[c];
        a += v * att_src[h * OC + c];
        b += v * att_dst[h * OC + c];
    }
    #pragma unroll
    for (int off = 32; off > 0; off >>= 1) {
        a += __shfl_down(a, off);
        b += __shfl_down(b, off);
    }
    if (lane == 0) { al[n * H + h] = a; ar[n * H + h] = b; }
}

// ---------------------------------------------------------------- edge softmax -> alpha[e,h]
// One wave per node. Lane = slot*HP + h (HP = heads padded to pow2).
// Pass 1: online (m,s) per head, butterfly-merged across slots.
// Pass 2: alpha[e*H+h] = exp(lg - m) / s.
template <int H, int HP, int LOG2HP>
__global__ __launch_bounds__(256) void attn_alpha_k(const int* __restrict__ rowptr,
                                                    const int* __restrict__ csr_src,
                                                    const float* __restrict__ al,
                                                    const float* __restrict__ ar,
                                                    float* __restrict__ alpha) {
    const int NSLOT = 64 / HP;
    int wid  = threadIdx.x >> 6;
    int lane = threadIdx.x & 63;
    int n = blockIdx.x * 4 + wid;
    if (n >= NN) return;
    int h    = lane & (HP - 1);
    int slot = lane >> LOG2HP;
    bool hv = (h < H);
    int beg = rowptr[n], end = rowptr[n + 1];
    float ard = hv ? ar[n * H + h] : 0.f;

    float m = -1e30f, s = 0.f;
    for (int e = beg + slot; e < end; e += NSLOT) {
        int src = csr_src[e];
        float lg = -1e30f;
        if (hv) {
            lg = al[src * H + h] + ard;
            lg = (lg > 0.f) ? lg : 0.2f * lg;
        }
        float mn = fmaxf(m, lg);
        s = s * __expf(m - mn) + (hv ? __expf(lg - mn) : 0.f);
        m = mn;
    }
    #pragma unroll
    for (int off = HP; off < 64; off <<= 1) {
        float mo = __shfl_xor(m, off);
        float so = __shfl_xor(s, off);
        float mn = fmaxf(m, mo);
        s = s * __expf(m - mn) + so * __expf(mo - mn);
        m = mn;
    }
    if (hv) {
        float inv = 1.f / s;           // s > 0 guaranteed (self-loop)
        for (int e = beg + slot; e < end; e += NSLOT) {
            int src = csr_src[e];
            float lg = al[src * H + h] + ard;
            lg = (lg > 0.f) ? lg : 0.2f * lg;
            alpha[(size_t)e * H + h] = __expf(lg - m) * inv;
        }
    }
}

// ---------------------------------------------------------------- gather (concat, H=4, OC=64)
__global__ __launch_bounds__(256) void gather_concat_k(const int* __restrict__ rowptr,
                                                       const int* __restrict__ csr_src,
                                                       const float* __restrict__ hfeat,
                                                       const float* __restrict__ alpha,
                                                       const float* __restrict__ bias,
                                                       float* __restrict__ out) {
    __shared__ int   s_src[64];
    __shared__ float4 s_a[64];
    int n = blockIdx.x;
    int tid = threadIdx.x;
    int head = tid >> 6;
    int beg = rowptr[n], end = rowptr[n + 1];
    float acc = 0.f;
    for (int c0 = beg; c0 < end; c0 += 64) {
        int cnt = min(64, end - c0);
        __syncthreads();
        if (tid < cnt) {
            s_src[tid] = csr_src[c0 + tid];
            s_a[tid]   = ((const float4*)alpha)[c0 + tid];
        }
        __syncthreads();
        for (int i = 0; i < cnt; ++i) {
            float a = ((const float*)&s_a[i])[head];
            acc += a * hfeat[(size_t)s_src[i] * 256 + tid];
        }
    }
    out[(size_t)n * 256 + tid] = acc + bias[tid];
}

// ---------------------------------------------------------------- gather (mean, H=6, OC=121)
__global__ __launch_bounds__(768) void gather_mean_k(const int* __restrict__ rowptr,
                                                     const int* __restrict__ csr_src,
                                                     const float* __restrict__ hfeat,
                                                     const float* __restrict__ alpha,
                                                     const float* __restrict__ bias,
                                                     float* __restrict__ out) {
    __shared__ float red[6 * 128];
    __shared__ int   s_src[64];
    __shared__ float s_a[64 * 6];
    int n = blockIdx.x;
    int tid = threadIdx.x;
    int head = tid >> 7;        // 0..5
    int c = tid & 127;
    bool active = (c < 121);
    int beg = rowptr[n], end = rowptr[n + 1];
    float acc = 0.f;
    for (int c0 = beg; c0 < end; c0 += 64) {
        int cnt = min(64, end - c0);
        __syncthreads();
        if (tid < cnt) s_src[tid] = csr_src[c0 + tid];
        if (tid < cnt * 6) s_a[tid] = alpha[(size_t)c0 * 6 + tid];
        __syncthreads();
        for (int i = 0; i < cnt; ++i) {
            float hv = active ? hfeat[(size_t)s_src[i] * 726 + head * 121 + c] : 0.f;
            acc += s_a[i * 6 + head] * hv;
        }
    }
    red[head * 128 + c] = acc;
    __syncthreads();
    if (head == 0 && active) {
        float t = 0.f;
        #pragma unroll
        for (int h2 = 0; h2 < 6; ++h2) t += red[h2 * 128 + c];
        out[(size_t)n * 121 + c] = t * (1.f / 6.f) + bias[c];
    }
}

// ---------------------------------------------------------------- launch
extern "C" void kernel_launch(void* const* d_in, const int* in_sizes, int n_in,
                              void* d_out, int out_size, void* d_ws, size_t ws_size,
                              hipStream_t stream) {
    const float* x   = (const float*)d_in[0];
    const int*   ei  = (const int*)d_in[1];
    const float* W1  = (const float*)d_in[2];
    const float* a1s = (const float*)d_in[3];
    const float* a1d = (const float*)d_in[4];
    const float* b1  = (const float*)d_in[5];
    const float* Wl1 = (const float*)d_in[6];
    const float* bl1 = (const float*)d_in[7];
    const float* W2  = (const float*)d_in[8];
    const float* a2s = (const float*)d_in[9];
    const float* a2d = (const float*)d_in[10];
    const float* b2  = (const float*)d_in[11];
    const float* Wl2 = (const float*)d_in[12];
    const float* bl2 = (const float*)d_in[13];
    const float* W3  = (const float*)d_in[14];
    const float* a3s = (const float*)d_in[15];
    const float* a3d = (const float*)d_in[16];
    const float* b3  = (const float*)d_in[17];
    const float* Wl3 = (const float*)d_in[18];
    const float* bl3 = (const float*)d_in[19];

    float* out    = (float*)d_out;                 // [40000,121]
    float* hidden = out + (size_t)NN * 121;        // [40000,256]

    // workspace layout
    char* ws = (char*)d_ws;
    size_t off = 0;
    auto alloc = [&](size_t bytes) { size_t o = off; off = (off + bytes + 255) & ~(size_t)255; return o; };
    int*   counts    = (int*)(ws + alloc((size_t)NN * 4));
    int*   rowptr    = (int*)(ws + alloc((size_t)(NN + 1) * 4));
    int*   blocksums = (int*)(ws + alloc(256 * 4));
    int*   csr_src   = (int*)(ws + alloc((size_t)ETOT * 4));
    float* al        = (float*)(ws + alloc((size_t)NN * 6 * 4));
    float* ar        = (float*)(ws + alloc((size_t)NN * 6 * 4));
    float* alpha     = (float*)(ws + alloc((size_t)ETOT * 6 * 4));
    float* hfeat     = (float*)(ws + alloc((size_t)NN * 726 * 4));
    float* h1        = (float*)(ws + alloc((size_t)NN * 256 * 4));

    const int eblocks = (ETOT + 255) / 256;
    const int ablocks = (NN + 3) / 4;

    // ---- CSR build (same for all layers)
    hipMemsetAsync(counts, 0, (size_t)NN * 4, stream);
    count_k<<<eblocks, 256, 0, stream>>>(ei, counts);
    scan_k<<<NBLK, 256, 0, stream>>>(counts, rowptr, blocksums, NN);
    scan_k<<<1, 256, 0, stream>>>(blocksums, blocksums, nullptr, NBLK);
    add_off_k<<<NBLK, 256, 0, stream>>>(rowptr, blocksums);
    hipMemsetAsync(counts, 0, (size_t)NN * 4, stream);  // reuse as cursor
    scatter_k<<<eblocks, 256, 0, stream>>>(ei, rowptr, counts, csr_src);

    // ---- Layer 1: in=x[N,50], out=h1[N,256]
    gemm_k<0><<<dim3(4, NN / 64), 256, 0, stream>>>(x, W1, nullptr, hfeat, NN, 256, 50);
    alar_k<<<dim3(4, NN), 64, 0, stream>>>(hfeat, a1s, a1d, al, ar, 4, 64);
    attn_alpha_k<4, 4, 2><<<ablocks, 256, 0, stream>>>(rowptr, csr_src, al, ar, alpha);
    gather_concat_k<<<NN, 256, 0, stream>>>(rowptr, csr_src, hfeat, alpha, b1, h1);
    gemm_k<1><<<dim3(4, NN / 64), 256, 0, stream>>>(x, Wl1, bl1, h1, NN, 256, 50);

    // ---- Layer 2: in=h1[N,256], out=hidden[N,256] (d_out)
    gemm_k<0><<<dim3(4, NN / 64), 256, 0, stream>>>(h1, W2, nullptr, hfeat, NN, 256, 256);
    alar_k<<<dim3(4, NN), 64, 0, stream>>>(hfeat, a2s, a2d, al, ar, 4, 64);
    attn_alpha_k<4, 4, 2><<<ablocks, 256, 0, stream>>>(rowptr, csr_src, al, ar, alpha);
    gather_concat_k<<<NN, 256, 0, stream>>>(rowptr, csr_src, hfeat, alpha, b2, hidden);
    gemm_k<1><<<dim3(4, NN / 64), 256, 0, stream>>>(h1, Wl2, bl2, hidden, NN, 256, 256);

    // ---- Layer 3: in=hidden[N,256], out=out[N,121] (mean over 6 heads)
    gemm_k<0><<<dim3(12, NN / 64), 256, 0, stream>>>(hidden, W3, nullptr, hfeat, NN, 726, 256);
    alar_k<<<dim3(6, NN), 64, 0, stream>>>(hfeat, a3s, a3d, al, ar, 6, 121);
    attn_alpha_k<6, 8, 3><<<ablocks, 256, 0, stream>>>(rowptr, csr_src, al, ar, alpha);
    gather_mean_k<<<NN, 768, 0, stream>>>(rowptr, csr_src, hfeat, alpha, b3, out);
    gemm_k<2><<<dim3(2, NN / 64), 256, 0, stream>>>(hidden, Wl3, bl3, out, NN, 121, 256);
}

// Round 3
// 1312.523 us; speedup vs baseline: 1.5873x; 1.1965x over previous
//
#include <hip/hip_runtime.h>
#include <math.h>

#define NN   40000
#define EE   640000
#define ETOT (EE + NN)          // 680000 edges incl self-loops
#define NBLK ((NN + 255) / 256) // 157

typedef short bf16x8 __attribute__((ext_vector_type(8)));
typedef float f32x4  __attribute__((ext_vector_type(4)));

__device__ __forceinline__ unsigned short f2bf(float f) {
    unsigned int u = __float_as_uint(f);
    u += 0x7fff + ((u >> 16) & 1);          // RNE
    return (unsigned short)(u >> 16);
}
__device__ __forceinline__ float bf2f(unsigned short h) {
    return __uint_as_float(((unsigned int)h) << 16);
}
__device__ __forceinline__ void cvt_hilo(float4 f, ushort4& hi, ushort4& lo) {
    hi.x = f2bf(f.x); lo.x = f2bf(f.x - bf2f(hi.x));
    hi.y = f2bf(f.y); lo.y = f2bf(f.y - bf2f(hi.y));
    hi.z = f2bf(f.z); lo.z = f2bf(f.z - bf2f(hi.z));
    hi.w = f2bf(f.w); lo.w = f2bf(f.w - bf2f(hi.w));
}
// guarded / alignment-aware 4-float load (zeros beyond `valid`)
__device__ __forceinline__ float4 load4(const float* __restrict__ p, int valid, int align) {
    float4 f = make_float4(0.f, 0.f, 0.f, 0.f);
    if (valid >= 4) {
        if (align == 4) {
            f = *(const float4*)p;
        } else if (align == 2) {
            float2 a = *(const float2*)p, b = *(const float2*)(p + 2);
            f.x = a.x; f.y = a.y; f.z = b.x; f.w = b.y;
        } else {
            f.x = p[0]; f.y = p[1]; f.z = p[2]; f.w = p[3];
        }
    } else {
        if (valid >= 1) f.x = p[0];
        if (valid >= 2) f.y = p[1];
        if (valid >= 3) f.z = p[2];
    }
    return f;
}

// ---------------------------------------------------------------- CSR build
__global__ void count_k(const int* __restrict__ ei, int* __restrict__ counts) {
    int e = blockIdx.x * 256 + threadIdx.x;
    if (e >= ETOT) return;
    int d = (e < EE) ? ei[EE + e] : (e - EE);
    atomicAdd(&counts[d], 1);
}

__global__ __launch_bounds__(256) void scan_k(const int* __restrict__ in,
                                              int* __restrict__ out,
                                              int* __restrict__ sums, int n) {
    __shared__ int tmp[256];
    int i = blockIdx.x * 256 + threadIdx.x;
    int v = (i < n) ? in[i] : 0;
    tmp[threadIdx.x] = v;
    __syncthreads();
    #pragma unroll
    for (int off = 1; off < 256; off <<= 1) {
        int t = (threadIdx.x >= off) ? tmp[threadIdx.x - off] : 0;
        __syncthreads();
        tmp[threadIdx.x] += t;
        __syncthreads();
    }
    if (i < n) out[i] = tmp[threadIdx.x] - v;   // exclusive
    if (sums != nullptr && threadIdx.x == 255) sums[blockIdx.x] = tmp[255];
}

__global__ void add_off_k(int* __restrict__ data, const int* __restrict__ offs) {
    int i = blockIdx.x * 256 + threadIdx.x;
    if (i < NN) data[i] += offs[blockIdx.x];
    if (blockIdx.x == 0 && threadIdx.x == 0) data[NN] = ETOT;
}

__global__ void scatter_k(const int* __restrict__ ei, const int* __restrict__ rowptr,
                          int* __restrict__ cursor, int* __restrict__ csr_src) {
    int e = blockIdx.x * 256 + threadIdx.x;
    if (e >= ETOT) return;
    int s, d;
    if (e < EE) { s = ei[e]; d = ei[EE + e]; } else { s = d = e - EE; }
    int pos = rowptr[d] + atomicAdd(&cursor[d], 1);
    csr_src[pos] = s;
}

// ---------------------------------------------------------------- MFMA GEMM (split bf16 hi/lo)
// C[M,N] = A[M,K] @ B[K,N]   (MODE 0: write; 1: C=elu(C+AB+bias); 2: C=C+AB+bias)
// 128x128 tile, BK=32, 4 waves in 2x2, each wave 64x64 via 4x4 16x16x32 frags.
// acc += Ahi*Bhi + Ahi*Blo + Alo*Bhi  (fp32-like accuracy, ~2^-17 rel err)
template <int MODE>
__global__ __launch_bounds__(256, 2) void gemm_mfma_k(const float* __restrict__ A,
                                                      const float* __restrict__ B,
                                                      const float* __restrict__ bias,
                                                      float* __restrict__ C,
                                                      int M, int N, int K) {
    __shared__ unsigned short Ahi[128 * 32], Alo[128 * 32];
    __shared__ unsigned short Bhi[128 * 32], Blo[128 * 32];
    const int tid  = threadIdx.x;
    const int lane = tid & 63;
    const int wv   = tid >> 6;
    const int wm   = wv >> 1, wn = wv & 1;
    const int r16  = lane & 15, kg = lane >> 4;
    const int bm   = blockIdx.y * 128, bn = blockIdx.x * 128;
    const int alignA = ((K & 3) == 0) ? 4 : (((K & 1) == 0) ? 2 : 1);
    const int alignB = ((N & 3) == 0) ? 4 : (((N & 1) == 0) ? 2 : 1);

    f32x4 acc[4][4];
    #pragma unroll
    for (int m = 0; m < 4; ++m)
        #pragma unroll
        for (int n = 0; n < 4; ++n) acc[m][n] = (f32x4){0.f, 0.f, 0.f, 0.f};

    for (int k0 = 0; k0 < K; k0 += 32) {
        // ---- stage A tile [128 rows][32 k] as bf16 hi/lo, swizzled 16B slots
        #pragma unroll
        for (int i = 0; i < 4; ++i) {
            int v  = tid + i * 256;            // float4 index 0..1023
            int r  = v >> 3, c4 = v & 7;       // row, float4-within-row
            int gr = bm + r, gk = k0 + c4 * 4;
            float4 f = make_float4(0.f, 0.f, 0.f, 0.f);
            if (gr < M && gk < K) f = load4(A + (size_t)gr * K + gk, K - gk, alignA);
            ushort4 hi, lo;
            cvt_hilo(f, hi, lo);
            int byte = r * 64 + ((((c4 >> 1) ^ (r & 3)) << 4)) + (c4 & 1) * 8;
            *(ushort4*)((char*)Ahi + byte) = hi;
            *(ushort4*)((char*)Alo + byte) = lo;
        }
        // ---- stage B tile [32 k][128 n] -> LDS as [n][k] via 4x4 register transpose
        {
            int n4 = (tid & 31) * 4, k4 = (tid >> 5) * 4;
            float4 rv[4];
            #pragma unroll
            for (int j = 0; j < 4; ++j) {
                int gk = k0 + k4 + j, gn = bn + n4;
                float4 f = make_float4(0.f, 0.f, 0.f, 0.f);
                if (gk < K && gn < N) f = load4(B + (size_t)gk * N + gn, N - gn, alignB);
                rv[j] = f;
            }
            #pragma unroll
            for (int c = 0; c < 4; ++c) {
                int n = n4 + c;
                float4 t = make_float4(((const float*)&rv[0])[c], ((const float*)&rv[1])[c],
                                       ((const float*)&rv[2])[c], ((const float*)&rv[3])[c]);
                ushort4 hi, lo;
                cvt_hilo(t, hi, lo);
                int byte = n * 64 + (((k4 >> 3) ^ (n & 3)) << 4) + ((k4 >> 2) & 1) * 8;
                *(ushort4*)((char*)Bhi + byte) = hi;
                *(ushort4*)((char*)Blo + byte) = lo;
            }
        }
        __syncthreads();
        // ---- fragments + MFMA
        bf16x8 fah[4], fal[4], fbh[4], fbl[4];
        const int slot = (kg ^ (r16 & 3)) << 4;
        #pragma unroll
        for (int m = 0; m < 4; ++m) {
            int byte = (wm * 64 + m * 16 + r16) * 64 + slot;
            fah[m] = *(const bf16x8*)((const char*)Ahi + byte);
            fal[m] = *(const bf16x8*)((const char*)Alo + byte);
        }
        #pragma unroll
        for (int n = 0; n < 4; ++n) {
            int byte = (wn * 64 + n * 16 + r16) * 64 + slot;
            fbh[n] = *(const bf16x8*)((const char*)Bhi + byte);
            fbl[n] = *(const bf16x8*)((const char*)Blo + byte);
        }
        #pragma unroll
        for (int m = 0; m < 4; ++m)
            #pragma unroll
            for (int n = 0; n < 4; ++n) {
                acc[m][n] = __builtin_amdgcn_mfma_f32_16x16x32_bf16(fah[m], fbh[n], acc[m][n], 0, 0, 0);
                acc[m][n] = __builtin_amdgcn_mfma_f32_16x16x32_bf16(fah[m], fbl[n], acc[m][n], 0, 0, 0);
                acc[m][n] = __builtin_amdgcn_mfma_f32_16x16x32_bf16(fal[m], fbh[n], acc[m][n], 0, 0, 0);
            }
        __syncthreads();
    }
    // ---- epilogue: D row = kg*4 + r, col = r16 within each 16x16 frag
    #pragma unroll
    for (int m = 0; m < 4; ++m) {
        #pragma unroll
        for (int r = 0; r < 4; ++r) {
            int gr = bm + wm * 64 + m * 16 + kg * 4 + r;
            if (gr >= M) continue;
            #pragma unroll
            for (int n = 0; n < 4; ++n) {
                int gc = bn + wn * 64 + n * 16 + r16;
                if (gc >= N) continue;
                size_t o = (size_t)gr * N + gc;
                float v = acc[m][n][r];
                if (MODE == 0) {
                    C[o] = v;
                } else {
                    float w = C[o] + v + bias[gc];
                    if (MODE == 1) w = (w > 0.f) ? w : expm1f(w);
                    C[o] = w;
                }
            }
        }
    }
}

// ---------------------------------------------------------------- attention coeffs
__global__ __launch_bounds__(64) void alar_k(const float* __restrict__ hfeat,
                                             const float* __restrict__ att_src,
                                             const float* __restrict__ att_dst,
                                             float* __restrict__ al, float* __restrict__ ar,
                                             int H, int OC) {
    int h = blockIdx.x;
    int n = blockIdx.y;
    int lane = threadIdx.x;
    const float* hp = hfeat + (size_t)n * H * OC + h * OC;
    float a = 0.f, b = 0.f;
    for (int c = lane; c < OC; c += 64) {
        float v = hp[c];
        a += v * att_src[h * OC + c];
        b += v * att_dst[h * OC + c];
    }
    #pragma unroll
    for (int off = 32; off > 0; off >>= 1) {
        a += __shfl_down(a, off);
        b += __shfl_down(b, off);
    }
    if (lane == 0) { al[n * H + h] = a; ar[n * H + h] = b; }
}

// ---------------------------------------------------------------- edge softmax -> alpha[e,h]
template <int H, int HP, int LOG2HP>
__global__ __launch_bounds__(256) void attn_alpha_k(const int* __restrict__ rowptr,
                                                    const int* __restrict__ csr_src,
                                                    const float* __restrict__ al,
                                                    const float* __restrict__ ar,
                                                    float* __restrict__ alpha) {
    const int NSLOT = 64 / HP;
    int wid  = threadIdx.x >> 6;
    int lane = threadIdx.x & 63;
    int n = blockIdx.x * 4 + wid;
    if (n >= NN) return;
    int h    = lane & (HP - 1);
    int slot = lane >> LOG2HP;
    bool hv = (h < H);
    int beg = rowptr[n], end = rowptr[n + 1];
    float ard = hv ? ar[n * H + h] : 0.f;

    float m = -1e30f, s = 0.f;
    for (int e = beg + slot; e < end; e += NSLOT) {
        int src = csr_src[e];
        float lg = -1e30f;
        if (hv) {
            lg = al[src * H + h] + ard;
            lg = (lg > 0.f) ? lg : 0.2f * lg;
        }
        float mn = fmaxf(m, lg);
        s = s * __expf(m - mn) + (hv ? __expf(lg - mn) : 0.f);
        m = mn;
    }
    #pragma unroll
    for (int off = HP; off < 64; off <<= 1) {
        float mo = __shfl_xor(m, off);
        float so = __shfl_xor(s, off);
        float mn = fmaxf(m, mo);
        s = s * __expf(m - mn) + so * __expf(mo - mn);
        m = mn;
    }
    if (hv) {
        float inv = 1.f / s;
        for (int e = beg + slot; e < end; e += NSLOT) {
            int src = csr_src[e];
            float lg = al[src * H + h] + ard;
            lg = (lg > 0.f) ? lg : 0.2f * lg;
            alpha[(size_t)e * H + h] = __expf(lg - m) * inv;
        }
    }
}

// ---------------------------------------------------------------- gather (concat, H=4, OC=64)
__global__ __launch_bounds__(256) void gather_concat_k(const int* __restrict__ rowptr,
                                                       const int* __restrict__ csr_src,
                                                       const float* __restrict__ hfeat,
                                                       const float* __restrict__ alpha,
                                                       const float* __restrict__ bias,
                                                       float* __restrict__ out) {
    __shared__ int    s_src[64];
    __shared__ float4 s_a[64];
    int n = blockIdx.x;
    int tid = threadIdx.x;
    int head = tid >> 6;
    int beg = rowptr[n], end = rowptr[n + 1];
    float acc = 0.f;
    for (int c0 = beg; c0 < end; c0 += 64) {
        int cnt = min(64, end - c0);
        __syncthreads();
        if (tid < cnt) {
            s_src[tid] = csr_src[c0 + tid];
            s_a[tid]   = ((const float4*)alpha)[c0 + tid];
        }
        __syncthreads();
        for (int i = 0; i < cnt; ++i) {
            float a = ((const float*)&s_a[i])[head];
            acc += a * hfeat[(size_t)s_src[i] * 256 + tid];
        }
    }
    out[(size_t)n * 256 + tid] = acc + bias[tid];
}

// ---------------------------------------------------------------- gather (mean, H=6, OC=121)
__global__ __launch_bounds__(768) void gather_mean_k(const int* __restrict__ rowptr,
                                                     const int* __restrict__ csr_src,
                                                     const float* __restrict__ hfeat,
                                                     const float* __restrict__ alpha,
                                                     const float* __restrict__ bias,
                                                     float* __restrict__ out) {
    __shared__ float red[6 * 128];
    __shared__ int   s_src[64];
    __shared__ float s_a[64 * 6];
    int n = blockIdx.x;
    int tid = threadIdx.x;
    int head = tid >> 7;        // 0..5
    int c = tid & 127;
    bool active = (c < 121);
    int beg = rowptr[n], end = rowptr[n + 1];
    float acc = 0.f;
    for (int c0 = beg; c0 < end; c0 += 64) {
        int cnt = min(64, end - c0);
        __syncthreads();
        if (tid < cnt) s_src[tid] = csr_src[c0 + tid];
        if (tid < cnt * 6) s_a[tid] = alpha[(size_t)c0 * 6 + tid];
        __syncthreads();
        for (int i = 0; i < cnt; ++i) {
            float hv = active ? hfeat[(size_t)s_src[i] * 726 + head * 121 + c] : 0.f;
            acc += s_a[i * 6 + head] * hv;
        }
    }
    red[head * 128 + c] = acc;
    __syncthreads();
    if (head == 0 && active) {
        float t = 0.f;
        #pragma unroll
        for (int h2 = 0; h2 < 6; ++h2) t += red[h2 * 128 + c];
        out[(size_t)n * 121 + c] = t * (1.f / 6.f) + bias[c];
    }
}

// ---------------------------------------------------------------- launch
extern "C" void kernel_launch(void* const* d_in, const int* in_sizes, int n_in,
                              void* d_out, int out_size, void* d_ws, size_t ws_size,
                              hipStream_t stream) {
    const float* x   = (const float*)d_in[0];
    const int*   ei  = (const int*)d_in[1];
    const float* W1  = (const float*)d_in[2];
    const float* a1s = (const float*)d_in[3];
    const float* a1d = (const float*)d_in[4];
    const float* b1  = (const float*)d_in[5];
    const float* Wl1 = (const float*)d_in[6];
    const float* bl1 = (const float*)d_in[7];
    const float* W2  = (const float*)d_in[8];
    const float* a2s = (const float*)d_in[9];
    const float* a2d = (const float*)d_in[10];
    const float* b2  = (const float*)d_in[11];
    const float* Wl2 = (const float*)d_in[12];
    const float* bl2 = (const float*)d_in[13];
    const float* W3  = (const float*)d_in[14];
    const float* a3s = (const float*)d_in[15];
    const float* a3d = (const float*)d_in[16];
    const float* b3  = (const float*)d_in[17];
    const float* Wl3 = (const float*)d_in[18];
    const float* bl3 = (const float*)d_in[19];

    float* out    = (float*)d_out;                 // [40000,121]
    float* hidden = out + (size_t)NN * 121;        // [40000,256]

    // workspace layout
    char* ws = (char*)d_ws;
    size_t off = 0;
    auto alloc = [&](size_t bytes) { size_t o = off; off = (off + bytes + 255) & ~(size_t)255; return o; };
    int*   counts    = (int*)(ws + alloc((size_t)NN * 4));
    int*   rowptr    = (int*)(ws + alloc((size_t)(NN + 1) * 4));
    int*   blocksums = (int*)(ws + alloc(256 * 4));
    int*   csr_src   = (int*)(ws + alloc((size_t)ETOT * 4));
    float* al        = (float*)(ws + alloc((size_t)NN * 6 * 4));
    float* ar        = (float*)(ws + alloc((size_t)NN * 6 * 4));
    float* alpha     = (float*)(ws + alloc((size_t)ETOT * 6 * 4));
    float* hfeat     = (float*)(ws + alloc((size_t)NN * 726 * 4));
    float* h1        = (float*)(ws + alloc((size_t)NN * 256 * 4));

    const int eblocks = (ETOT + 255) / 256;
    const int ablocks = (NN + 3) / 4;
    const int mg = (NN + 127) / 128;   // 313

    // ---- CSR build (same for all layers)
    hipMemsetAsync(counts, 0, (size_t)NN * 4, stream);
    count_k<<<eblocks, 256, 0, stream>>>(ei, counts);
    scan_k<<<NBLK, 256, 0, stream>>>(counts, rowptr, blocksums, NN);
    scan_k<<<1, 256, 0, stream>>>(blocksums, blocksums, nullptr, NBLK);
    add_off_k<<<NBLK, 256, 0, stream>>>(rowptr, blocksums);
    hipMemsetAsync(counts, 0, (size_t)NN * 4, stream);  // reuse as cursor
    scatter_k<<<eblocks, 256, 0, stream>>>(ei, rowptr, counts, csr_src);

    // ---- Layer 1: in=x[N,50], out=h1[N,256]
    gemm_mfma_k<0><<<dim3(2, mg), 256, 0, stream>>>(x, W1, nullptr, hfeat, NN, 256, 50);
    alar_k<<<dim3(4, NN), 64, 0, stream>>>(hfeat, a1s, a1d, al, ar, 4, 64);
    attn_alpha_k<4, 4, 2><<<ablocks, 256, 0, stream>>>(rowptr, csr_src, al, ar, alpha);
    gather_concat_k<<<NN, 256, 0, stream>>>(rowptr, csr_src, hfeat, alpha, b1, h1);
    gemm_mfma_k<1><<<dim3(2, mg), 256, 0, stream>>>(x, Wl1, bl1, h1, NN, 256, 50);

    // ---- Layer 2: in=h1[N,256], out=hidden[N,256] (d_out)
    gemm_mfma_k<0><<<dim3(2, mg), 256, 0, stream>>>(h1, W2, nullptr, hfeat, NN, 256, 256);
    alar_k<<<dim3(4, NN), 64, 0, stream>>>(hfeat, a2s, a2d, al, ar, 4, 64);
    attn_alpha_k<4, 4, 2><<<ablocks, 256, 0, stream>>>(rowptr, csr_src, al, ar, alpha);
    gather_concat_k<<<NN, 256, 0, stream>>>(rowptr, csr_src, hfeat, alpha, b2, hidden);
    gemm_mfma_k<1><<<dim3(2, mg), 256, 0, stream>>>(h1, Wl2, bl2, hidden, NN, 256, 256);

    // ---- Layer 3: in=hidden[N,256], out=out[N,121] (mean over 6 heads)
    gemm_mfma_k<0><<<dim3(6, mg), 256, 0, stream>>>(hidden, W3, nullptr, hfeat, NN, 726, 256);
    alar_k<<<dim3(6, NN), 64, 0, stream>>>(hfeat, a3s, a3d, al, ar, 6, 121);
    attn_alpha_k<6, 8, 3><<<ablocks, 256, 0, stream>>>(rowptr, csr_src, al, ar, alpha);
    gather_mean_k<<<NN, 768, 0, stream>>>(rowptr, csr_src, hfeat, alpha, b3, out);
    gemm_mfma_k<2><<<dim3(1, mg), 256, 0, stream>>>(hidden, Wl3, bl3, out, NN, 121, 256);
}

// Round 4
// 1274.911 us; speedup vs baseline: 1.6342x; 1.0295x over previous
//
#include <hip/hip_runtime.h>
#include <math.h>

#define NN   40000
#define EE   640000
#define ETOT (EE + NN)          // 680000 edges incl self-loops
#define NBLK ((NN + 255) / 256) // 157

typedef short bf16x8 __attribute__((ext_vector_type(8)));
typedef float f32x4  __attribute__((ext_vector_type(4)));

__device__ __forceinline__ unsigned short f2bf(float f) {
    unsigned int u = __float_as_uint(f);
    u += 0x7fff + ((u >> 16) & 1);          // RNE
    return (unsigned short)(u >> 16);
}
__device__ __forceinline__ float bf2f(unsigned short h) {
    return __uint_as_float(((unsigned int)h) << 16);
}
__device__ __forceinline__ void cvt_hilo(float4 f, ushort4& hi, ushort4& lo) {
    hi.x = f2bf(f.x); lo.x = f2bf(f.x - bf2f(hi.x));
    hi.y = f2bf(f.y); lo.y = f2bf(f.y - bf2f(hi.y));
    hi.z = f2bf(f.z); lo.z = f2bf(f.z - bf2f(hi.z));
    hi.w = f2bf(f.w); lo.w = f2bf(f.w - bf2f(hi.w));
}
// guarded / alignment-aware 4-float load (zeros beyond `valid`)
__device__ __forceinline__ float4 load4(const float* __restrict__ p, int valid, int align) {
    float4 f = make_float4(0.f, 0.f, 0.f, 0.f);
    if (valid >= 4) {
        if (align == 4) {
            f = *(const float4*)p;
        } else if (align == 2) {
            float2 a = *(const float2*)p, b = *(const float2*)(p + 2);
            f.x = a.x; f.y = a.y; f.z = b.x; f.w = b.y;
        } else {
            f.x = p[0]; f.y = p[1]; f.z = p[2]; f.w = p[3];
        }
    } else {
        if (valid >= 1) f.x = p[0];
        if (valid >= 2) f.y = p[1];
        if (valid >= 3) f.z = p[2];
    }
    return f;
}

// ---------------------------------------------------------------- CSR build
__global__ void count_k(const int* __restrict__ ei, int* __restrict__ counts) {
    int e = blockIdx.x * 256 + threadIdx.x;
    if (e >= ETOT) return;
    int d = (e < EE) ? ei[EE + e] : (e - EE);
    atomicAdd(&counts[d], 1);
}

__global__ __launch_bounds__(256) void scan_k(const int* __restrict__ in,
                                              int* __restrict__ out,
                                              int* __restrict__ sums, int n) {
    __shared__ int tmp[256];
    int i = blockIdx.x * 256 + threadIdx.x;
    int v = (i < n) ? in[i] : 0;
    tmp[threadIdx.x] = v;
    __syncthreads();
    #pragma unroll
    for (int off = 1; off < 256; off <<= 1) {
        int t = (threadIdx.x >= off) ? tmp[threadIdx.x - off] : 0;
        __syncthreads();
        tmp[threadIdx.x] += t;
        __syncthreads();
    }
    if (i < n) out[i] = tmp[threadIdx.x] - v;   // exclusive
    if (sums != nullptr && threadIdx.x == 255) sums[blockIdx.x] = tmp[255];
}

__global__ void add_off_k(int* __restrict__ data, const int* __restrict__ offs) {
    int i = blockIdx.x * 256 + threadIdx.x;
    if (i < NN) data[i] += offs[blockIdx.x];
    if (blockIdx.x == 0 && threadIdx.x == 0) data[NN] = ETOT;
}

__global__ void scatter_k(const int* __restrict__ ei, const int* __restrict__ rowptr,
                          int* __restrict__ cursor, int* __restrict__ csr_src) {
    int e = blockIdx.x * 256 + threadIdx.x;
    if (e >= ETOT) return;
    int s, d;
    if (e < EE) { s = ei[e]; d = ei[EE + e]; } else { s = d = e - EE; }
    int pos = rowptr[d] + atomicAdd(&cursor[d], 1);
    csr_src[pos] = s;
}

// ---------------------------------------------------------------- MFMA GEMM (split bf16 hi/lo)
// C[M,N] = A[M,K] @ B[K,N]
// MODE 0: C=AB (f32); 1: C=elu(C+AB+bias); 2: C=C+AB+bias; 3: C=AB as bf16 (ushort*)
template <int MODE>
__global__ __launch_bounds__(256, 2) void gemm_mfma_k(const float* __restrict__ A,
                                                      const float* __restrict__ B,
                                                      const float* __restrict__ bias,
                                                      float* __restrict__ C,
                                                      int M, int N, int K) {
    __shared__ unsigned short Ahi[128 * 32], Alo[128 * 32];
    __shared__ unsigned short Bhi[128 * 32], Blo[128 * 32];
    const int tid  = threadIdx.x;
    const int lane = tid & 63;
    const int wv   = tid >> 6;
    const int wm   = wv >> 1, wn = wv & 1;
    const int r16  = lane & 15, kg = lane >> 4;
    const int bm   = blockIdx.y * 128, bn = blockIdx.x * 128;
    const int alignA = ((K & 3) == 0) ? 4 : (((K & 1) == 0) ? 2 : 1);
    const int alignB = ((N & 3) == 0) ? 4 : (((N & 1) == 0) ? 2 : 1);

    f32x4 acc[4][4];
    #pragma unroll
    for (int m = 0; m < 4; ++m)
        #pragma unroll
        for (int n = 0; n < 4; ++n) acc[m][n] = (f32x4){0.f, 0.f, 0.f, 0.f};

    for (int k0 = 0; k0 < K; k0 += 32) {
        // ---- stage A tile [128 rows][32 k] as bf16 hi/lo, swizzled 16B slots
        #pragma unroll
        for (int i = 0; i < 4; ++i) {
            int v  = tid + i * 256;            // float4 index 0..1023
            int r  = v >> 3, c4 = v & 7;       // row, float4-within-row
            int gr = bm + r, gk = k0 + c4 * 4;
            float4 f = make_float4(0.f, 0.f, 0.f, 0.f);
            if (gr < M && gk < K) f = load4(A + (size_t)gr * K + gk, K - gk, alignA);
            ushort4 hi, lo;
            cvt_hilo(f, hi, lo);
            int byte = r * 64 + ((((c4 >> 1) ^ (r & 3)) << 4)) + (c4 & 1) * 8;
            *(ushort4*)((char*)Ahi + byte) = hi;
            *(ushort4*)((char*)Alo + byte) = lo;
        }
        // ---- stage B tile [32 k][128 n] -> LDS as [n][k] via 4x4 register transpose
        {
            int n4 = (tid & 31) * 4, k4 = (tid >> 5) * 4;
            float4 rv[4];
            #pragma unroll
            for (int j = 0; j < 4; ++j) {
                int gk = k0 + k4 + j, gn = bn + n4;
                float4 f = make_float4(0.f, 0.f, 0.f, 0.f);
                if (gk < K && gn < N) f = load4(B + (size_t)gk * N + gn, N - gn, alignB);
                rv[j] = f;
            }
            #pragma unroll
            for (int c = 0; c < 4; ++c) {
                int n = n4 + c;
                float4 t = make_float4(((const float*)&rv[0])[c], ((const float*)&rv[1])[c],
                                       ((const float*)&rv[2])[c], ((const float*)&rv[3])[c]);
                ushort4 hi, lo;
                cvt_hilo(t, hi, lo);
                int byte = n * 64 + (((k4 >> 3) ^ (n & 3)) << 4) + ((k4 >> 2) & 1) * 8;
                *(ushort4*)((char*)Bhi + byte) = hi;
                *(ushort4*)((char*)Blo + byte) = lo;
            }
        }
        __syncthreads();
        // ---- fragments + MFMA
        bf16x8 fah[4], fal[4], fbh[4], fbl[4];
        const int slot = (kg ^ (r16 & 3)) << 4;
        #pragma unroll
        for (int m = 0; m < 4; ++m) {
            int byte = (wm * 64 + m * 16 + r16) * 64 + slot;
            fah[m] = *(const bf16x8*)((const char*)Ahi + byte);
            fal[m] = *(const bf16x8*)((const char*)Alo + byte);
        }
        #pragma unroll
        for (int n = 0; n < 4; ++n) {
            int byte = (wn * 64 + n * 16 + r16) * 64 + slot;
            fbh[n] = *(const bf16x8*)((const char*)Bhi + byte);
            fbl[n] = *(const bf16x8*)((const char*)Blo + byte);
        }
        #pragma unroll
        for (int m = 0; m < 4; ++m)
            #pragma unroll
            for (int n = 0; n < 4; ++n) {
                acc[m][n] = __builtin_amdgcn_mfma_f32_16x16x32_bf16(fah[m], fbh[n], acc[m][n], 0, 0, 0);
                acc[m][n] = __builtin_amdgcn_mfma_f32_16x16x32_bf16(fah[m], fbl[n], acc[m][n], 0, 0, 0);
                acc[m][n] = __builtin_amdgcn_mfma_f32_16x16x32_bf16(fal[m], fbh[n], acc[m][n], 0, 0, 0);
            }
        __syncthreads();
    }
    // ---- epilogue: D row = kg*4 + r, col = r16 within each 16x16 frag
    #pragma unroll
    for (int m = 0; m < 4; ++m) {
        #pragma unroll
        for (int r = 0; r < 4; ++r) {
            int gr = bm + wm * 64 + m * 16 + kg * 4 + r;
            if (gr >= M) continue;
            #pragma unroll
            for (int n = 0; n < 4; ++n) {
                int gc = bn + wn * 64 + n * 16 + r16;
                if (gc >= N) continue;
                size_t o = (size_t)gr * N + gc;
                float v = acc[m][n][r];
                if (MODE == 0) {
                    C[o] = v;
                } else if (MODE == 3) {
                    ((unsigned short*)C)[o] = f2bf(v);
                } else {
                    float w = C[o] + v + bias[gc];
                    if (MODE == 1) w = (w > 0.f) ? w : expm1f(w);
                    C[o] = w;
                }
            }
        }
    }
}

// ---------------------------------------------------------------- attention coeffs (bf16 feat)
__global__ __launch_bounds__(64) void alar_k(const unsigned short* __restrict__ hfeat,
                                             const float* __restrict__ att_src,
                                             const float* __restrict__ att_dst,
                                             float* __restrict__ al, float* __restrict__ ar,
                                             int H, int OC) {
    int h = blockIdx.x;
    int n = blockIdx.y;
    int lane = threadIdx.x;
    const unsigned short* hp = hfeat + (size_t)n * H * OC + h * OC;
    float a = 0.f, b = 0.f;
    for (int c = lane; c < OC; c += 64) {
        float v = bf2f(hp[c]);
        a += v * att_src[h * OC + c];
        b += v * att_dst[h * OC + c];
    }
    #pragma unroll
    for (int off = 32; off > 0; off >>= 1) {
        a += __shfl_down(a, off);
        b += __shfl_down(b, off);
    }
    if (lane == 0) { al[n * H + h] = a; ar[n * H + h] = b; }
}

// ---------------------------------------------------------------- edge softmax -> alpha[e,h]
template <int H, int HP, int LOG2HP>
__global__ __launch_bounds__(256) void attn_alpha_k(const int* __restrict__ rowptr,
                                                    const int* __restrict__ csr_src,
                                                    const float* __restrict__ al,
                                                    const float* __restrict__ ar,
                                                    float* __restrict__ alpha) {
    const int NSLOT = 64 / HP;
    int wid  = threadIdx.x >> 6;
    int lane = threadIdx.x & 63;
    int n = blockIdx.x * 4 + wid;
    if (n >= NN) return;
    int h    = lane & (HP - 1);
    int slot = lane >> LOG2HP;
    bool hv = (h < H);
    int beg = rowptr[n], end = rowptr[n + 1];
    float ard = hv ? ar[n * H + h] : 0.f;

    float m = -1e30f, s = 0.f;
    for (int e = beg + slot; e < end; e += NSLOT) {
        int src = csr_src[e];
        float lg = -1e30f;
        if (hv) {
            lg = al[src * H + h] + ard;
            lg = (lg > 0.f) ? lg : 0.2f * lg;
        }
        float mn = fmaxf(m, lg);
        s = s * __expf(m - mn) + (hv ? __expf(lg - mn) : 0.f);
        m = mn;
    }
    #pragma unroll
    for (int off = HP; off < 64; off <<= 1) {
        float mo = __shfl_xor(m, off);
        float so = __shfl_xor(s, off);
        float mn = fmaxf(m, mo);
        s = s * __expf(m - mn) + so * __expf(mo - mn);
        m = mn;
    }
    if (hv) {
        float inv = 1.f / s;
        for (int e = beg + slot; e < end; e += NSLOT) {
            int src = csr_src[e];
            float lg = al[src * H + h] + ard;
            lg = (lg > 0.f) ? lg : 0.2f * lg;
            alpha[(size_t)e * H + h] = __expf(lg - m) * inv;
        }
    }
}

// ---------------------------------------------------------------- gather (concat, H=4, 256ch bf16)
// 2 edge-lanes x 128 positions x 2 channels (ushort2 loads)
__global__ __launch_bounds__(256) void gather_concat_k(const int* __restrict__ rowptr,
                                                       const int* __restrict__ csr_src,
                                                       const unsigned short* __restrict__ hfeat,
                                                       const float* __restrict__ alpha,
                                                       const float* __restrict__ bias,
                                                       float* __restrict__ out) {
    __shared__ int    s_src[64];
    __shared__ float4 s_a[64];
    __shared__ float  s_red[256];
    int n = blockIdx.x;
    int tid = threadIdx.x;
    int elane = tid >> 7;          // 0/1
    int pos   = tid & 127;         // channel pair index
    int head  = pos >> 5;          // (2*pos)/64
    int beg = rowptr[n], end = rowptr[n + 1];
    float acc0 = 0.f, acc1 = 0.f;
    for (int c0 = beg; c0 < end; c0 += 64) {
        int cnt = min(64, end - c0);
        __syncthreads();
        if (tid < cnt) {
            s_src[tid] = csr_src[c0 + tid];
            s_a[tid]   = ((const float4*)alpha)[c0 + tid];
        }
        __syncthreads();
        for (int i = 0; i < cnt; i += 2) {
            int e = i + elane;
            if (e < cnt) {
                float a = ((const float*)&s_a[e])[head];
                ushort2 u = *(const ushort2*)(hfeat + (size_t)s_src[e] * 256 + pos * 2);
                acc0 += a * bf2f(u.x);
                acc1 += a * bf2f(u.y);
            }
        }
    }
    __syncthreads();
    if (elane == 0) { s_red[pos * 2] = acc0; s_red[pos * 2 + 1] = acc1; }
    __syncthreads();
    if (elane == 1) { s_red[pos * 2] += acc0; s_red[pos * 2 + 1] += acc1; }
    __syncthreads();
    out[(size_t)n * 256 + tid] = s_red[tid] + bias[tid];
}

// ---------------------------------------------------------------- gather (mean, H=6, 726ch bf16)
// 363 active threads x 2 channels (ushort2); per-thread head lookup
__global__ __launch_bounds__(384) void gather_mean_k(const int* __restrict__ rowptr,
                                                     const int* __restrict__ csr_src,
                                                     const unsigned short* __restrict__ hfeat,
                                                     const float* __restrict__ alpha,
                                                     const float* __restrict__ bias,
                                                     float* __restrict__ out) {
    __shared__ float red[726];
    __shared__ int   s_src[64];
    __shared__ float s_a[64 * 6];
    int n = blockIdx.x;
    int tid = threadIdx.x;
    int p0 = tid * 2, p1 = p0 + 1;
    bool act = (p0 < 726);
    int h0 = act ? (p0 / 121) : 0;
    int h1 = act ? (p1 / 121) : 0;
    int beg = rowptr[n], end = rowptr[n + 1];
    float acc0 = 0.f, acc1 = 0.f;
    for (int c0 = beg; c0 < end; c0 += 64) {
        int cnt = min(64, end - c0);
        __syncthreads();
        if (tid < cnt) s_src[tid] = csr_src[c0 + tid];
        if (tid < cnt * 6) s_a[tid] = alpha[(size_t)c0 * 6 + tid];
        __syncthreads();
        for (int i = 0; i < cnt; ++i) {
            if (act) {
                ushort2 u = *(const ushort2*)(hfeat + (size_t)s_src[i] * 726 + p0);
                acc0 += s_a[i * 6 + h0] * bf2f(u.x);
                acc1 += s_a[i * 6 + h1] * bf2f(u.y);
            }
        }
    }
    __syncthreads();
    if (act) { red[p0] = acc0; red[p1] = acc1; }
    __syncthreads();
    if (tid < 121) {
        float t = 0.f;
        #pragma unroll
        for (int h2 = 0; h2 < 6; ++h2) t += red[tid + 121 * h2];
        out[(size_t)n * 121 + tid] = t * (1.f / 6.f) + bias[tid];
    }
}

// ---------------------------------------------------------------- launch
extern "C" void kernel_launch(void* const* d_in, const int* in_sizes, int n_in,
                              void* d_out, int out_size, void* d_ws, size_t ws_size,
                              hipStream_t stream) {
    const float* x   = (const float*)d_in[0];
    const int*   ei  = (const int*)d_in[1];
    const float* W1  = (const float*)d_in[2];
    const float* a1s = (const float*)d_in[3];
    const float* a1d = (const float*)d_in[4];
    const float* b1  = (const float*)d_in[5];
    const float* Wl1 = (const float*)d_in[6];
    const float* bl1 = (const float*)d_in[7];
    const float* W2  = (const float*)d_in[8];
    const float* a2s = (const float*)d_in[9];
    const float* a2d = (const float*)d_in[10];
    const float* b2  = (const float*)d_in[11];
    const float* Wl2 = (const float*)d_in[12];
    const float* bl2 = (const float*)d_in[13];
    const float* W3  = (const float*)d_in[14];
    const float* a3s = (const float*)d_in[15];
    const float* a3d = (const float*)d_in[16];
    const float* b3  = (const float*)d_in[17];
    const float* Wl3 = (const float*)d_in[18];
    const float* bl3 = (const float*)d_in[19];

    float* out    = (float*)d_out;                 // [40000,121]
    float* hidden = out + (size_t)NN * 121;        // [40000,256]

    // workspace layout
    char* ws = (char*)d_ws;
    size_t off = 0;
    auto alloc = [&](size_t bytes) { size_t o = off; off = (off + bytes + 255) & ~(size_t)255; return o; };
    int*   counts    = (int*)(ws + alloc((size_t)NN * 4));
    int*   rowptr    = (int*)(ws + alloc((size_t)(NN + 1) * 4));
    int*   blocksums = (int*)(ws + alloc(256 * 4));
    int*   csr_src   = (int*)(ws + alloc((size_t)ETOT * 4));
    float* al        = (float*)(ws + alloc((size_t)NN * 6 * 4));
    float* ar        = (float*)(ws + alloc((size_t)NN * 6 * 4));
    float* alpha     = (float*)(ws + alloc((size_t)ETOT * 6 * 4));
    unsigned short* hfeatb = (unsigned short*)(ws + alloc((size_t)NN * 726 * 2));
    float* h1        = (float*)(ws + alloc((size_t)NN * 256 * 4));

    const int eblocks = (ETOT + 255) / 256;
    const int ablocks = (NN + 3) / 4;
    const int mg = (NN + 127) / 128;   // 313

    // ---- CSR build (same for all layers)
    hipMemsetAsync(counts, 0, (size_t)NN * 4, stream);
    count_k<<<eblocks, 256, 0, stream>>>(ei, counts);
    scan_k<<<NBLK, 256, 0, stream>>>(counts, rowptr, blocksums, NN);
    scan_k<<<1, 256, 0, stream>>>(blocksums, blocksums, nullptr, NBLK);
    add_off_k<<<NBLK, 256, 0, stream>>>(rowptr, blocksums);
    hipMemsetAsync(counts, 0, (size_t)NN * 4, stream);  // reuse as cursor
    scatter_k<<<eblocks, 256, 0, stream>>>(ei, rowptr, counts, csr_src);

    // ---- Layer 1: in=x[N,50], out=h1[N,256]
    gemm_mfma_k<3><<<dim3(2, mg), 256, 0, stream>>>(x, W1, nullptr, (float*)hfeatb, NN, 256, 50);
    alar_k<<<dim3(4, NN), 64, 0, stream>>>(hfeatb, a1s, a1d, al, ar, 4, 64);
    attn_alpha_k<4, 4, 2><<<ablocks, 256, 0, stream>>>(rowptr, csr_src, al, ar, alpha);
    gather_concat_k<<<NN, 256, 0, stream>>>(rowptr, csr_src, hfeatb, alpha, b1, h1);
    gemm_mfma_k<1><<<dim3(2, mg), 256, 0, stream>>>(x, Wl1, bl1, h1, NN, 256, 50);

    // ---- Layer 2: in=h1[N,256], out=hidden[N,256] (d_out)
    gemm_mfma_k<3><<<dim3(2, mg), 256, 0, stream>>>(h1, W2, nullptr, (float*)hfeatb, NN, 256, 256);
    alar_k<<<dim3(4, NN), 64, 0, stream>>>(hfeatb, a2s, a2d, al, ar, 4, 64);
    attn_alpha_k<4, 4, 2><<<ablocks, 256, 0, stream>>>(rowptr, csr_src, al, ar, alpha);
    gather_concat_k<<<NN, 256, 0, stream>>>(rowptr, csr_src, hfeatb, alpha, b2, hidden);
    gemm_mfma_k<1><<<dim3(2, mg), 256, 0, stream>>>(h1, Wl2, bl2, hidden, NN, 256, 256);

    // ---- Layer 3: in=hidden[N,256], out=out[N,121] (mean over 6 heads)
    gemm_mfma_k<3><<<dim3(6, mg), 256, 0, stream>>>(hidden, W3, nullptr, (float*)hfeatb, NN, 726, 256);
    alar_k<<<dim3(6, NN), 64, 0, stream>>>(hfeatb, a3s, a3d, al, ar, 6, 121);
    attn_alpha_k<6, 8, 3><<<ablocks, 256, 0, stream>>>(rowptr, csr_src, al, ar, alpha);
    gather_mean_k<<<NN, 384, 0, stream>>>(rowptr, csr_src, hfeatb, alpha, b3, out);
    gemm_mfma_k<2><<<dim3(1, mg), 256, 0, stream>>>(hidden, Wl3, bl3, out, NN, 121, 256);
}

// Round 5
// 1072.390 us; speedup vs baseline: 1.9428x; 1.1888x over previous
//
#include <hip/hip_runtime.h>
#include <math.h>

#define NN   40000
#define EE   640000
#define ETOT (EE + NN)          // 680000 edges incl self-loops
#define NBLK ((NN + 255) / 256) // 157

typedef short bf16x8 __attribute__((ext_vector_type(8)));
typedef float f32x4  __attribute__((ext_vector_type(4)));

__device__ __forceinline__ unsigned short f2bf(float f) {
    unsigned int u = __float_as_uint(f);
    u += 0x7fff + ((u >> 16) & 1);          // RNE
    return (unsigned short)(u >> 16);
}
__device__ __forceinline__ float bf2f(unsigned short h) {
    return __uint_as_float(((unsigned int)h) << 16);
}
__device__ __forceinline__ void cvt_hilo(float4 f, ushort4& hi, ushort4& lo) {
    hi.x = f2bf(f.x); lo.x = f2bf(f.x - bf2f(hi.x));
    hi.y = f2bf(f.y); lo.y = f2bf(f.y - bf2f(hi.y));
    hi.z = f2bf(f.z); lo.z = f2bf(f.z - bf2f(hi.z));
    hi.w = f2bf(f.w); lo.w = f2bf(f.w - bf2f(hi.w));
}
// guarded / alignment-aware 4-float load (zeros beyond `valid`)
__device__ __forceinline__ float4 load4(const float* __restrict__ p, int valid, int align) {
    float4 f = make_float4(0.f, 0.f, 0.f, 0.f);
    if (valid >= 4) {
        if (align == 4) {
            f = *(const float4*)p;
        } else if (align == 2) {
            float2 a = *(const float2*)p, b = *(const float2*)(p + 2);
            f.x = a.x; f.y = a.y; f.z = b.x; f.w = b.y;
        } else {
            f.x = p[0]; f.y = p[1]; f.z = p[2]; f.w = p[3];
        }
    } else {
        if (valid >= 1) f.x = p[0];
        if (valid >= 2) f.y = p[1];
        if (valid >= 3) f.z = p[2];
    }
    return f;
}

// ---------------------------------------------------------------- CSR build
__global__ void count_k(const int* __restrict__ ei, int* __restrict__ counts) {
    int e = blockIdx.x * 256 + threadIdx.x;
    if (e >= ETOT) return;
    int d = (e < EE) ? ei[EE + e] : (e - EE);
    atomicAdd(&counts[d], 1);
}

__global__ __launch_bounds__(256) void scan_k(const int* __restrict__ in,
                                              int* __restrict__ out,
                                              int* __restrict__ sums, int n) {
    __shared__ int tmp[256];
    int i = blockIdx.x * 256 + threadIdx.x;
    int v = (i < n) ? in[i] : 0;
    tmp[threadIdx.x] = v;
    __syncthreads();
    #pragma unroll
    for (int off = 1; off < 256; off <<= 1) {
        int t = (threadIdx.x >= off) ? tmp[threadIdx.x - off] : 0;
        __syncthreads();
        tmp[threadIdx.x] += t;
        __syncthreads();
    }
    if (i < n) out[i] = tmp[threadIdx.x] - v;   // exclusive
    if (sums != nullptr && threadIdx.x == 255) sums[blockIdx.x] = tmp[255];
}

__global__ void add_off_k(int* __restrict__ data, const int* __restrict__ offs) {
    int i = blockIdx.x * 256 + threadIdx.x;
    if (i < NN) data[i] += offs[blockIdx.x];
    if (blockIdx.x == 0 && threadIdx.x == 0) data[NN] = ETOT;
}

__global__ void scatter_k(const int* __restrict__ ei, const int* __restrict__ rowptr,
                          int* __restrict__ cursor, int* __restrict__ csr_src) {
    int e = blockIdx.x * 256 + threadIdx.x;
    if (e >= ETOT) return;
    int s, d;
    if (e < EE) { s = ei[e]; d = ei[EE + e]; } else { s = d = e - EE; }
    int pos = rowptr[d] + atomicAdd(&cursor[d], 1);
    csr_src[pos] = s;
}

// ---------------------------------------------------------------- MFMA GEMM (split bf16 hi/lo)
// C[M,N] = A[M,K] @ B[K,N]
// MODE 0: C=AB (f32); 1: C=elu(C+AB+bias); 2: C=C+AB+bias; 3: C=AB as bf16 (ushort*)
template <int MODE>
__global__ __launch_bounds__(256, 2) void gemm_mfma_k(const float* __restrict__ A,
                                                      const float* __restrict__ B,
                                                      const float* __restrict__ bias,
                                                      float* __restrict__ C,
                                                      int M, int N, int K) {
    __shared__ unsigned short Ahi[128 * 32], Alo[128 * 32];
    __shared__ unsigned short Bhi[128 * 32], Blo[128 * 32];
    const int tid  = threadIdx.x;
    const int lane = tid & 63;
    const int wv   = tid >> 6;
    const int wm   = wv >> 1, wn = wv & 1;
    const int r16  = lane & 15, kg = lane >> 4;
    const int bm   = blockIdx.y * 128, bn = blockIdx.x * 128;
    const int alignA = ((K & 3) == 0) ? 4 : (((K & 1) == 0) ? 2 : 1);
    const int alignB = ((N & 3) == 0) ? 4 : (((N & 1) == 0) ? 2 : 1);

    f32x4 acc[4][4];
    #pragma unroll
    for (int m = 0; m < 4; ++m)
        #pragma unroll
        for (int n = 0; n < 4; ++n) acc[m][n] = (f32x4){0.f, 0.f, 0.f, 0.f};

    for (int k0 = 0; k0 < K; k0 += 32) {
        // ---- stage A tile [128 rows][32 k] as bf16 hi/lo, swizzled 16B slots
        #pragma unroll
        for (int i = 0; i < 4; ++i) {
            int v  = tid + i * 256;            // float4 index 0..1023
            int r  = v >> 3, c4 = v & 7;       // row, float4-within-row
            int gr = bm + r, gk = k0 + c4 * 4;
            float4 f = make_float4(0.f, 0.f, 0.f, 0.f);
            if (gr < M && gk < K) f = load4(A + (size_t)gr * K + gk, K - gk, alignA);
            ushort4 hi, lo;
            cvt_hilo(f, hi, lo);
            int byte = r * 64 + ((((c4 >> 1) ^ (r & 3)) << 4)) + (c4 & 1) * 8;
            *(ushort4*)((char*)Ahi + byte) = hi;
            *(ushort4*)((char*)Alo + byte) = lo;
        }
        // ---- stage B tile [32 k][128 n] -> LDS as [n][k] via 4x4 register transpose
        {
            int n4 = (tid & 31) * 4, k4 = (tid >> 5) * 4;
            float4 rv[4];
            #pragma unroll
            for (int j = 0; j < 4; ++j) {
                int gk = k0 + k4 + j, gn = bn + n4;
                float4 f = make_float4(0.f, 0.f, 0.f, 0.f);
                if (gk < K && gn < N) f = load4(B + (size_t)gk * N + gn, N - gn, alignB);
                rv[j] = f;
            }
            #pragma unroll
            for (int c = 0; c < 4; ++c) {
                int n = n4 + c;
                float4 t = make_float4(((const float*)&rv[0])[c], ((const float*)&rv[1])[c],
                                       ((const float*)&rv[2])[c], ((const float*)&rv[3])[c]);
                ushort4 hi, lo;
                cvt_hilo(t, hi, lo);
                int byte = n * 64 + (((k4 >> 3) ^ (n & 3)) << 4) + ((k4 >> 2) & 1) * 8;
                *(ushort4*)((char*)Bhi + byte) = hi;
                *(ushort4*)((char*)Blo + byte) = lo;
            }
        }
        __syncthreads();
        // ---- fragments + MFMA
        bf16x8 fah[4], fal[4], fbh[4], fbl[4];
        const int slot = (kg ^ (r16 & 3)) << 4;
        #pragma unroll
        for (int m = 0; m < 4; ++m) {
            int byte = (wm * 64 + m * 16 + r16) * 64 + slot;
            fah[m] = *(const bf16x8*)((const char*)Ahi + byte);
            fal[m] = *(const bf16x8*)((const char*)Alo + byte);
        }
        #pragma unroll
        for (int n = 0; n < 4; ++n) {
            int byte = (wn * 64 + n * 16 + r16) * 64 + slot;
            fbh[n] = *(const bf16x8*)((const char*)Bhi + byte);
            fbl[n] = *(const bf16x8*)((const char*)Blo + byte);
        }
        #pragma unroll
        for (int m = 0; m < 4; ++m)
            #pragma unroll
            for (int n = 0; n < 4; ++n) {
                acc[m][n] = __builtin_amdgcn_mfma_f32_16x16x32_bf16(fah[m], fbh[n], acc[m][n], 0, 0, 0);
                acc[m][n] = __builtin_amdgcn_mfma_f32_16x16x32_bf16(fah[m], fbl[n], acc[m][n], 0, 0, 0);
                acc[m][n] = __builtin_amdgcn_mfma_f32_16x16x32_bf16(fal[m], fbh[n], acc[m][n], 0, 0, 0);
            }
        __syncthreads();
    }
    // ---- epilogue: D row = kg*4 + r, col = r16 within each 16x16 frag
    #pragma unroll
    for (int m = 0; m < 4; ++m) {
        #pragma unroll
        for (int r = 0; r < 4; ++r) {
            int gr = bm + wm * 64 + m * 16 + kg * 4 + r;
            if (gr >= M) continue;
            #pragma unroll
            for (int n = 0; n < 4; ++n) {
                int gc = bn + wn * 64 + n * 16 + r16;
                if (gc >= N) continue;
                size_t o = (size_t)gr * N + gc;
                float v = acc[m][n][r];
                if (MODE == 0) {
                    C[o] = v;
                } else if (MODE == 3) {
                    ((unsigned short*)C)[o] = f2bf(v);
                } else {
                    float w = C[o] + v + bias[gc];
                    if (MODE == 1) w = (w > 0.f) ? w : expm1f(w);
                    C[o] = w;
                }
            }
        }
    }
}

// ---------------------------------------------------------------- attention coeffs (bf16 feat)
__global__ __launch_bounds__(64) void alar_k(const unsigned short* __restrict__ hfeat,
                                             const float* __restrict__ att_src,
                                             const float* __restrict__ att_dst,
                                             float* __restrict__ al, float* __restrict__ ar,
                                             int H, int OC) {
    int h = blockIdx.x;
    int n = blockIdx.y;
    int lane = threadIdx.x;
    const unsigned short* hp = hfeat + (size_t)n * H * OC + h * OC;
    float a = 0.f, b = 0.f;
    for (int c = lane; c < OC; c += 64) {
        float v = bf2f(hp[c]);
        a += v * att_src[h * OC + c];
        b += v * att_dst[h * OC + c];
    }
    #pragma unroll
    for (int off = 32; off > 0; off >>= 1) {
        a += __shfl_down(a, off);
        b += __shfl_down(b, off);
    }
    if (lane == 0) { al[n * H + h] = a; ar[n * H + h] = b; }
}

// ---------------------------------------------------------------- edge softmax -> alpha[e,h]
template <int H, int HP, int LOG2HP>
__global__ __launch_bounds__(256) void attn_alpha_k(const int* __restrict__ rowptr,
                                                    const int* __restrict__ csr_src,
                                                    const float* __restrict__ al,
                                                    const float* __restrict__ ar,
                                                    float* __restrict__ alpha) {
    const int NSLOT = 64 / HP;
    int wid  = threadIdx.x >> 6;
    int lane = threadIdx.x & 63;
    int n = blockIdx.x * 4 + wid;
    if (n >= NN) return;
    int h    = lane & (HP - 1);
    int slot = lane >> LOG2HP;
    bool hv = (h < H);
    int beg = rowptr[n], end = rowptr[n + 1];
    float ard = hv ? ar[n * H + h] : 0.f;

    float m = -1e30f, s = 0.f;
    for (int e = beg + slot; e < end; e += NSLOT) {
        int src = csr_src[e];
        float lg = -1e30f;
        if (hv) {
            lg = al[src * H + h] + ard;
            lg = (lg > 0.f) ? lg : 0.2f * lg;
        }
        float mn = fmaxf(m, lg);
        s = s * __expf(m - mn) + (hv ? __expf(lg - mn) : 0.f);
        m = mn;
    }
    #pragma unroll
    for (int off = HP; off < 64; off <<= 1) {
        float mo = __shfl_xor(m, off);
        float so = __shfl_xor(s, off);
        float mn = fmaxf(m, mo);
        s = s * __expf(m - mn) + so * __expf(mo - mn);
        m = mn;
    }
    if (hv) {
        float inv = 1.f / s;
        for (int e = beg + slot; e < end; e += NSLOT) {
            int src = csr_src[e];
            float lg = al[src * H + h] + ard;
            lg = (lg > 0.f) ? lg : 0.2f * lg;
            alpha[(size_t)e * H + h] = __expf(lg - m) * inv;
        }
    }
}

// ---------------------------------------------------------------- gather (concat, H=4, 256ch bf16)
// 2 nodes per 256-block; 128 lanes x ushort2 per node. No LDS, no barriers.
// Edge loop is wave-uniform: csr_src loads become scalar; unroll-4 for MLP.
__global__ __launch_bounds__(256) void gather_concat_k(const int* __restrict__ rowptr,
                                                       const int* __restrict__ csr_src,
                                                       const unsigned short* __restrict__ hfeat,
                                                       const float* __restrict__ alpha,
                                                       const float* __restrict__ bias,
                                                       float* __restrict__ out) {
    int n   = blockIdx.x * 2 + (threadIdx.x >> 7);
    int pos = threadIdx.x & 127;           // ushort2 channel pair 0..127
    int head = pos >> 5;
    int beg = rowptr[n], end = rowptr[n + 1];
    float acc0 = 0.f, acc1 = 0.f;
    int e = beg;
    for (; e + 4 <= end; e += 4) {
        int s0 = csr_src[e], s1 = csr_src[e + 1], s2 = csr_src[e + 2], s3 = csr_src[e + 3];
        float a0 = alpha[(size_t)(e + 0) * 4 + head];
        float a1 = alpha[(size_t)(e + 1) * 4 + head];
        float a2 = alpha[(size_t)(e + 2) * 4 + head];
        float a3 = alpha[(size_t)(e + 3) * 4 + head];
        ushort2 u0 = *(const ushort2*)(hfeat + (size_t)s0 * 256 + pos * 2);
        ushort2 u1 = *(const ushort2*)(hfeat + (size_t)s1 * 256 + pos * 2);
        ushort2 u2 = *(const ushort2*)(hfeat + (size_t)s2 * 256 + pos * 2);
        ushort2 u3 = *(const ushort2*)(hfeat + (size_t)s3 * 256 + pos * 2);
        acc0 += a0 * bf2f(u0.x) + a1 * bf2f(u1.x) + a2 * bf2f(u2.x) + a3 * bf2f(u3.x);
        acc1 += a0 * bf2f(u0.y) + a1 * bf2f(u1.y) + a2 * bf2f(u2.y) + a3 * bf2f(u3.y);
    }
    for (; e < end; ++e) {
        int s = csr_src[e];
        float a = alpha[(size_t)e * 4 + head];
        ushort2 u = *(const ushort2*)(hfeat + (size_t)s * 256 + pos * 2);
        acc0 += a * bf2f(u.x);
        acc1 += a * bf2f(u.y);
    }
    float2 r;
    r.x = acc0 + bias[pos * 2];
    r.y = acc1 + bias[pos * 2 + 1];
    *(float2*)(out + (size_t)n * 256 + pos * 2) = r;
}

// ---------------------------------------------------------------- gather (mean, H=6, 726ch bf16)
// 363 active lanes x ushort2; direct scalar/vector loads, unroll-4; single final barrier.
__global__ __launch_bounds__(384) void gather_mean_k(const int* __restrict__ rowptr,
                                                     const int* __restrict__ csr_src,
                                                     const unsigned short* __restrict__ hfeat,
                                                     const float* __restrict__ alpha,
                                                     const float* __restrict__ bias,
                                                     float* __restrict__ out) {
    __shared__ float red[726];
    int n = blockIdx.x;
    int tid = threadIdx.x;
    int p0 = tid * 2, p1 = p0 + 1;
    bool act = (p0 < 726);
    int q0 = act ? p0 : 0;
    int h0 = q0 / 121, h1 = (q0 + 1) / 121;
    int beg = rowptr[n], end = rowptr[n + 1];
    float acc0 = 0.f, acc1 = 0.f;
    int e = beg;
    for (; e + 4 <= end; e += 4) {
        int s0 = csr_src[e], s1 = csr_src[e + 1], s2 = csr_src[e + 2], s3 = csr_src[e + 3];
        float a00 = alpha[(size_t)(e + 0) * 6 + h0], a01 = alpha[(size_t)(e + 0) * 6 + h1];
        float a10 = alpha[(size_t)(e + 1) * 6 + h0], a11 = alpha[(size_t)(e + 1) * 6 + h1];
        float a20 = alpha[(size_t)(e + 2) * 6 + h0], a21 = alpha[(size_t)(e + 2) * 6 + h1];
        float a30 = alpha[(size_t)(e + 3) * 6 + h0], a31 = alpha[(size_t)(e + 3) * 6 + h1];
        ushort2 u0 = *(const ushort2*)(hfeat + (size_t)s0 * 726 + q0);
        ushort2 u1 = *(const ushort2*)(hfeat + (size_t)s1 * 726 + q0);
        ushort2 u2 = *(const ushort2*)(hfeat + (size_t)s2 * 726 + q0);
        ushort2 u3 = *(const ushort2*)(hfeat + (size_t)s3 * 726 + q0);
        acc0 += a00 * bf2f(u0.x) + a10 * bf2f(u1.x) + a20 * bf2f(u2.x) + a30 * bf2f(u3.x);
        acc1 += a01 * bf2f(u0.y) + a11 * bf2f(u1.y) + a21 * bf2f(u2.y) + a31 * bf2f(u3.y);
    }
    for (; e < end; ++e) {
        int s = csr_src[e];
        float a0 = alpha[(size_t)e * 6 + h0], a1 = alpha[(size_t)e * 6 + h1];
        ushort2 u = *(const ushort2*)(hfeat + (size_t)s * 726 + q0);
        acc0 += a0 * bf2f(u.x);
        acc1 += a1 * bf2f(u.y);
    }
    if (act) { red[p0] = acc0; red[p1] = acc1; }
    __syncthreads();
    if (tid < 121) {
        float t = 0.f;
        #pragma unroll
        for (int h2 = 0; h2 < 6; ++h2) t += red[tid + 121 * h2];
        out[(size_t)n * 121 + tid] = t * (1.f / 6.f) + bias[tid];
    }
}

// ---------------------------------------------------------------- launch
extern "C" void kernel_launch(void* const* d_in, const int* in_sizes, int n_in,
                              void* d_out, int out_size, void* d_ws, size_t ws_size,
                              hipStream_t stream) {
    const float* x   = (const float*)d_in[0];
    const int*   ei  = (const int*)d_in[1];
    const float* W1  = (const float*)d_in[2];
    const float* a1s = (const float*)d_in[3];
    const float* a1d = (const float*)d_in[4];
    const float* b1  = (const float*)d_in[5];
    const float* Wl1 = (const float*)d_in[6];
    const float* bl1 = (const float*)d_in[7];
    const float* W2  = (const float*)d_in[8];
    const float* a2s = (const float*)d_in[9];
    const float* a2d = (const float*)d_in[10];
    const float* b2  = (const float*)d_in[11];
    const float* Wl2 = (const float*)d_in[12];
    const float* bl2 = (const float*)d_in[13];
    const float* W3  = (const float*)d_in[14];
    const float* a3s = (const float*)d_in[15];
    const float* a3d = (const float*)d_in[16];
    const float* b3  = (const float*)d_in[17];
    const float* Wl3 = (const float*)d_in[18];
    const float* bl3 = (const float*)d_in[19];

    float* out    = (float*)d_out;                 // [40000,121]
    float* hidden = out + (size_t)NN * 121;        // [40000,256]

    // workspace layout
    char* ws = (char*)d_ws;
    size_t off = 0;
    auto alloc = [&](size_t bytes) { size_t o = off; off = (off + bytes + 255) & ~(size_t)255; return o; };
    int*   counts    = (int*)(ws + alloc((size_t)NN * 4));
    int*   rowptr    = (int*)(ws + alloc((size_t)(NN + 1) * 4));
    int*   blocksums = (int*)(ws + alloc(256 * 4));
    int*   csr_src   = (int*)(ws + alloc((size_t)ETOT * 4));
    float* al        = (float*)(ws + alloc((size_t)NN * 6 * 4));
    float* ar        = (float*)(ws + alloc((size_t)NN * 6 * 4));
    float* alpha     = (float*)(ws + alloc((size_t)ETOT * 6 * 4));
    unsigned short* hfeatb = (unsigned short*)(ws + alloc((size_t)NN * 726 * 2));
    float* h1        = (float*)(ws + alloc((size_t)NN * 256 * 4));

    const int eblocks = (ETOT + 255) / 256;
    const int ablocks = (NN + 3) / 4;
    const int mg = (NN + 127) / 128;   // 313

    // ---- CSR build (same for all layers)
    hipMemsetAsync(counts, 0, (size_t)NN * 4, stream);
    count_k<<<eblocks, 256, 0, stream>>>(ei, counts);
    scan_k<<<NBLK, 256, 0, stream>>>(counts, rowptr, blocksums, NN);
    scan_k<<<1, 256, 0, stream>>>(blocksums, blocksums, nullptr, NBLK);
    add_off_k<<<NBLK, 256, 0, stream>>>(rowptr, blocksums);
    hipMemsetAsync(counts, 0, (size_t)NN * 4, stream);  // reuse as cursor
    scatter_k<<<eblocks, 256, 0, stream>>>(ei, rowptr, counts, csr_src);

    // ---- Layer 1: in=x[N,50], out=h1[N,256]
    gemm_mfma_k<3><<<dim3(2, mg), 256, 0, stream>>>(x, W1, nullptr, (float*)hfeatb, NN, 256, 50);
    alar_k<<<dim3(4, NN), 64, 0, stream>>>(hfeatb, a1s, a1d, al, ar, 4, 64);
    attn_alpha_k<4, 4, 2><<<ablocks, 256, 0, stream>>>(rowptr, csr_src, al, ar, alpha);
    gather_concat_k<<<NN / 2, 256, 0, stream>>>(rowptr, csr_src, hfeatb, alpha, b1, h1);
    gemm_mfma_k<1><<<dim3(2, mg), 256, 0, stream>>>(x, Wl1, bl1, h1, NN, 256, 50);

    // ---- Layer 2: in=h1[N,256], out=hidden[N,256] (d_out)
    gemm_mfma_k<3><<<dim3(2, mg), 256, 0, stream>>>(h1, W2, nullptr, (float*)hfeatb, NN, 256, 256);
    alar_k<<<dim3(4, NN), 64, 0, stream>>>(hfeatb, a2s, a2d, al, ar, 4, 64);
    attn_alpha_k<4, 4, 2><<<ablocks, 256, 0, stream>>>(rowptr, csr_src, al, ar, alpha);
    gather_concat_k<<<NN / 2, 256, 0, stream>>>(rowptr, csr_src, hfeatb, alpha, b2, hidden);
    gemm_mfma_k<1><<<dim3(2, mg), 256, 0, stream>>>(h1, Wl2, bl2, hidden, NN, 256, 256);

    // ---- Layer 3: in=hidden[N,256], out=out[N,121] (mean over 6 heads)
    gemm_mfma_k<3><<<dim3(6, mg), 256, 0, stream>>>(hidden, W3, nullptr, (float*)hfeatb, NN, 726, 256);
    alar_k<<<dim3(6, NN), 64, 0, stream>>>(hfeatb, a3s, a3d, al, ar, 6, 121);
    attn_alpha_k<6, 8, 3><<<ablocks, 256, 0, stream>>>(rowptr, csr_src, al, ar, alpha);
    gather_mean_k<<<NN, 384, 0, stream>>>(rowptr, csr_src, hfeatb, alpha, b3, out);
    gemm_mfma_k<2><<<dim3(1, mg), 256, 0, stream>>>(hidden, Wl3, bl3, out, NN, 121, 256);
}

// Round 6
// 839.234 us; speedup vs baseline: 2.4825x; 1.2778x over previous
//
#include <hip/hip_runtime.h>
#include <math.h>

#define NN   40000
#define EE   640000
#define ETOT (EE + NN)          // 680000 edges incl self-loops
#define NBLK ((NN + 255) / 256) // 157

typedef short bf16x8 __attribute__((ext_vector_type(8)));
typedef float f32x4  __attribute__((ext_vector_type(4)));

__device__ __forceinline__ unsigned short f2bf(float f) {
    unsigned int u = __float_as_uint(f);
    u += 0x7fff + ((u >> 16) & 1);          // RNE
    return (unsigned short)(u >> 16);
}
__device__ __forceinline__ float bf2f(unsigned short h) {
    return __uint_as_float(((unsigned int)h) << 16);
}

// ---------------------------------------------------------------- CSR build
__global__ void count_k(const int* __restrict__ ei, int* __restrict__ counts) {
    int e = blockIdx.x * 256 + threadIdx.x;
    if (e >= ETOT) return;
    int d = (e < EE) ? ei[EE + e] : (e - EE);
    atomicAdd(&counts[d], 1);
}

__global__ __launch_bounds__(256) void scan_k(const int* __restrict__ in,
                                              int* __restrict__ out,
                                              int* __restrict__ sums, int n) {
    __shared__ int tmp[256];
    int i = blockIdx.x * 256 + threadIdx.x;
    int v = (i < n) ? in[i] : 0;
    tmp[threadIdx.x] = v;
    __syncthreads();
    #pragma unroll
    for (int off = 1; off < 256; off <<= 1) {
        int t = (threadIdx.x >= off) ? tmp[threadIdx.x - off] : 0;
        __syncthreads();
        tmp[threadIdx.x] += t;
        __syncthreads();
    }
    if (i < n) out[i] = tmp[threadIdx.x] - v;   // exclusive
    if (sums != nullptr && threadIdx.x == 255) sums[blockIdx.x] = tmp[255];
}

__global__ void add_off_k(int* __restrict__ data, const int* __restrict__ offs) {
    int i = blockIdx.x * 256 + threadIdx.x;
    if (i < NN) data[i] += offs[blockIdx.x];
    if (blockIdx.x == 0 && threadIdx.x == 0) data[NN] = ETOT;
}

__global__ void scatter_k(const int* __restrict__ ei, const int* __restrict__ rowptr,
                          int* __restrict__ cursor, int* __restrict__ csr_src) {
    int e = blockIdx.x * 256 + threadIdx.x;
    if (e >= ETOT) return;
    int s, d;
    if (e < EE) { s = ei[e]; d = ei[EE + e]; } else { s = d = e - EE; }
    int pos = rowptr[d] + atomicAdd(&cursor[d], 1);
    csr_src[pos] = s;
}

// ---------------------------------------------------------------- prep: fp32 -> bf16 (padded / transposed)
// x [NN][50] f32 -> xb [NN][64] bf16 (zero pad)
__global__ __launch_bounds__(256) void xprep_k(const float* __restrict__ x,
                                               unsigned short* __restrict__ xb) {
    int idx = blockIdx.x * 256 + threadIdx.x;   // NN*64 total
    if (idx >= NN * 64) return;
    int m = idx >> 6, k = idx & 63;
    xb[idx] = (k < 50) ? f2bf(x[(size_t)m * 50 + k]) : (unsigned short)0;
}

// W [K][N] f32 -> Wt [N][Kp] bf16 (zero pad K..Kp)
__global__ void wprep_k(const float* __restrict__ W, unsigned short* __restrict__ Wt,
                        int K, int N, int Kp) {
    int n = blockIdx.x;
    for (int k = threadIdx.x; k < Kp; k += blockDim.x)
        Wt[(size_t)n * Kp + k] = (k < K) ? f2bf(W[(size_t)k * N + n]) : (unsigned short)0;
}

// ---------------------------------------------------------------- bf16 MFMA GEMM
// C[M,N] = A[M,K] @ Bt[N,K]^T.  A,Bt bf16 row-major; K % 32 == 0.
// MODE 0: C=AB f32       | MODE 3: Cb=AB bf16
// MODE 1: Cb=elu(Cb+AB+bias) bf16 in/out
// MODE 4: w=elu(C+AB+bias); C=w (f32) and Cb=w (bf16)
// MODE 2: C=C+AB+bias (f32)
template <int MODE>
__global__ __launch_bounds__(256, 4) void gemm_bf16_k(const unsigned short* __restrict__ A,
                                                      const unsigned short* __restrict__ Bt,
                                                      const float* __restrict__ bias,
                                                      float* __restrict__ C,
                                                      unsigned short* __restrict__ Cb,
                                                      int M, int N, int K) {
    // 80B row stride (40 shorts): ds_read_b128 start banks spread evenly
    __shared__ unsigned short As[128 * 40];
    __shared__ unsigned short Bs[128 * 40];
    const int tid  = threadIdx.x;
    const int lane = tid & 63;
    const int wv   = tid >> 6;
    const int wm   = wv >> 1, wn = wv & 1;
    const int r16  = lane & 15, kg = lane >> 4;
    const int bm   = blockIdx.y * 128, bn = blockIdx.x * 128;

    f32x4 acc[4][4];
    #pragma unroll
    for (int m = 0; m < 4; ++m)
        #pragma unroll
        for (int n = 0; n < 4; ++n) acc[m][n] = (f32x4){0.f, 0.f, 0.f, 0.f};

    const bf16x8 zero8 = (bf16x8){0,0,0,0,0,0,0,0};
    for (int k0 = 0; k0 < K; k0 += 32) {
        // stage A + B tiles: 512 chunks of 16B each, 2 per thread per tile
        #pragma unroll
        for (int i = 0; i < 2; ++i) {
            int idx = tid + i * 256;            // 0..511
            int r = idx >> 2, c = idx & 3;      // row, 16B chunk
            int gr = bm + r;
            bf16x8 v = zero8;
            if (gr < M) v = *(const bf16x8*)(A + (size_t)gr * K + k0 + c * 8);
            *(bf16x8*)((char*)As + r * 80 + c * 16) = v;
            int gn = bn + r;
            bf16x8 w = zero8;
            if (gn < N) w = *(const bf16x8*)(Bt + (size_t)gn * K + k0 + c * 8);
            *(bf16x8*)((char*)Bs + r * 80 + c * 16) = w;
        }
        __syncthreads();
        bf16x8 fa[4], fb[4];
        #pragma unroll
        for (int m = 0; m < 4; ++m)
            fa[m] = *(const bf16x8*)((const char*)As + (wm * 64 + m * 16 + r16) * 80 + kg * 16);
        #pragma unroll
        for (int n = 0; n < 4; ++n)
            fb[n] = *(const bf16x8*)((const char*)Bs + (wn * 64 + n * 16 + r16) * 80 + kg * 16);
        #pragma unroll
        for (int m = 0; m < 4; ++m)
            #pragma unroll
            for (int n = 0; n < 4; ++n)
                acc[m][n] = __builtin_amdgcn_mfma_f32_16x16x32_bf16(fa[m], fb[n], acc[m][n], 0, 0, 0);
        __syncthreads();
    }
    // epilogue: within 16x16 frag, row = kg*4 + r, col = r16
    #pragma unroll
    for (int m = 0; m < 4; ++m) {
        #pragma unroll
        for (int r = 0; r < 4; ++r) {
            int gr = bm + wm * 64 + m * 16 + kg * 4 + r;
            if (gr >= M) continue;
            #pragma unroll
            for (int n = 0; n < 4; ++n) {
                int gc = bn + wn * 64 + n * 16 + r16;
                if (gc >= N) continue;
                size_t o = (size_t)gr * N + gc;
                float v = acc[m][n][r];
                if (MODE == 0) {
                    C[o] = v;
                } else if (MODE == 3) {
                    Cb[o] = f2bf(v);
                } else if (MODE == 1) {
                    float w = bf2f(Cb[o]) + v + bias[gc];
                    w = (w > 0.f) ? w : expm1f(w);
                    Cb[o] = f2bf(w);
                } else if (MODE == 4) {
                    float w = C[o] + v + bias[gc];
                    w = (w > 0.f) ? w : expm1f(w);
                    C[o] = w;
                    Cb[o] = f2bf(w);
                } else {  // MODE 2
                    C[o] = C[o] + v + bias[gc];
                }
            }
        }
    }
}

// ---------------------------------------------------------------- attention coeffs (bf16 feat)
__global__ __launch_bounds__(64) void alar_k(const unsigned short* __restrict__ hfeat,
                                             const float* __restrict__ att_src,
                                             const float* __restrict__ att_dst,
                                             float* __restrict__ al, float* __restrict__ ar,
                                             int H, int OC) {
    int h = blockIdx.x;
    int n = blockIdx.y;
    int lane = threadIdx.x;
    const unsigned short* hp = hfeat + (size_t)n * H * OC + h * OC;
    float a = 0.f, b = 0.f;
    for (int c = lane; c < OC; c += 64) {
        float v = bf2f(hp[c]);
        a += v * att_src[h * OC + c];
        b += v * att_dst[h * OC + c];
    }
    #pragma unroll
    for (int off = 32; off > 0; off >>= 1) {
        a += __shfl_down(a, off);
        b += __shfl_down(b, off);
    }
    if (lane == 0) { al[n * H + h] = a; ar[n * H + h] = b; }
}

// ---------------------------------------------------------------- edge softmax -> alpha[e,h]
template <int H, int HP, int LOG2HP>
__global__ __launch_bounds__(256) void attn_alpha_k(const int* __restrict__ rowptr,
                                                    const int* __restrict__ csr_src,
                                                    const float* __restrict__ al,
                                                    const float* __restrict__ ar,
                                                    float* __restrict__ alpha) {
    const int NSLOT = 64 / HP;
    int wid  = threadIdx.x >> 6;
    int lane = threadIdx.x & 63;
    int n = blockIdx.x * 4 + wid;
    if (n >= NN) return;
    int h    = lane & (HP - 1);
    int slot = lane >> LOG2HP;
    bool hv = (h < H);
    int beg = rowptr[n], end = rowptr[n + 1];
    float ard = hv ? ar[n * H + h] : 0.f;

    float m = -1e30f, s = 0.f;
    for (int e = beg + slot; e < end; e += NSLOT) {
        int src = csr_src[e];
        float lg = -1e30f;
        if (hv) {
            lg = al[src * H + h] + ard;
            lg = (lg > 0.f) ? lg : 0.2f * lg;
        }
        float mn = fmaxf(m, lg);
        s = s * __expf(m - mn) + (hv ? __expf(lg - mn) : 0.f);
        m = mn;
    }
    #pragma unroll
    for (int off = HP; off < 64; off <<= 1) {
        float mo = __shfl_xor(m, off);
        float so = __shfl_xor(s, off);
        float mn = fmaxf(m, mo);
        s = s * __expf(m - mn) + so * __expf(mo - mn);
        m = mn;
    }
    if (hv) {
        float inv = 1.f / s;
        for (int e = beg + slot; e < end; e += NSLOT) {
            int src = csr_src[e];
            float lg = al[src * H + h] + ard;
            lg = (lg > 0.f) ? lg : 0.2f * lg;
            alpha[(size_t)e * H + h] = __expf(lg - m) * inv;
        }
    }
}

// ---------------------------------------------------------------- gather (concat, H=4, 256ch bf16)
// 2 nodes per 256-block; 128 lanes x ushort2 per node. No LDS, no barriers.
// OUTB: write bf16 (h1 path) else fp32.
template <bool OUTB>
__global__ __launch_bounds__(256) void gather_concat_k(const int* __restrict__ rowptr,
                                                       const int* __restrict__ csr_src,
                                                       const unsigned short* __restrict__ hfeat,
                                                       const float* __restrict__ alpha,
                                                       const float* __restrict__ bias,
                                                       float* __restrict__ out,
                                                       unsigned short* __restrict__ outb) {
    int n   = blockIdx.x * 2 + (threadIdx.x >> 7);
    int pos = threadIdx.x & 127;           // ushort2 channel pair 0..127
    int head = pos >> 5;
    int beg = rowptr[n], end = rowptr[n + 1];
    float acc0 = 0.f, acc1 = 0.f;
    int e = beg;
    for (; e + 4 <= end; e += 4) {
        int s0 = csr_src[e], s1 = csr_src[e + 1], s2 = csr_src[e + 2], s3 = csr_src[e + 3];
        float a0 = alpha[(size_t)(e + 0) * 4 + head];
        float a1 = alpha[(size_t)(e + 1) * 4 + head];
        float a2 = alpha[(size_t)(e + 2) * 4 + head];
        float a3 = alpha[(size_t)(e + 3) * 4 + head];
        ushort2 u0 = *(const ushort2*)(hfeat + (size_t)s0 * 256 + pos * 2);
        ushort2 u1 = *(const ushort2*)(hfeat + (size_t)s1 * 256 + pos * 2);
        ushort2 u2 = *(const ushort2*)(hfeat + (size_t)s2 * 256 + pos * 2);
        ushort2 u3 = *(const ushort2*)(hfeat + (size_t)s3 * 256 + pos * 2);
        acc0 += a0 * bf2f(u0.x) + a1 * bf2f(u1.x) + a2 * bf2f(u2.x) + a3 * bf2f(u3.x);
        acc1 += a0 * bf2f(u0.y) + a1 * bf2f(u1.y) + a2 * bf2f(u2.y) + a3 * bf2f(u3.y);
    }
    for (; e < end; ++e) {
        int s = csr_src[e];
        float a = alpha[(size_t)e * 4 + head];
        ushort2 u = *(const ushort2*)(hfeat + (size_t)s * 256 + pos * 2);
        acc0 += a * bf2f(u.x);
        acc1 += a * bf2f(u.y);
    }
    acc0 += bias[pos * 2];
    acc1 += bias[pos * 2 + 1];
    if (OUTB) {
        ushort2 r;
        r.x = f2bf(acc0);
        r.y = f2bf(acc1);
        *(ushort2*)(outb + (size_t)n * 256 + pos * 2) = r;
    } else {
        float2 r;
        r.x = acc0; r.y = acc1;
        *(float2*)(out + (size_t)n * 256 + pos * 2) = r;
    }
}

// ---------------------------------------------------------------- gather (mean, H=6, 726ch bf16)
__global__ __launch_bounds__(384) void gather_mean_k(const int* __restrict__ rowptr,
                                                     const int* __restrict__ csr_src,
                                                     const unsigned short* __restrict__ hfeat,
                                                     const float* __restrict__ alpha,
                                                     const float* __restrict__ bias,
                                                     float* __restrict__ out) {
    __shared__ float red[726];
    int n = blockIdx.x;
    int tid = threadIdx.x;
    int p0 = tid * 2, p1 = p0 + 1;
    bool act = (p0 < 726);
    int q0 = act ? p0 : 0;
    int h0 = q0 / 121, h1 = (q0 + 1) / 121;
    int beg = rowptr[n], end = rowptr[n + 1];
    float acc0 = 0.f, acc1 = 0.f;
    int e = beg;
    for (; e + 4 <= end; e += 4) {
        int s0 = csr_src[e], s1 = csr_src[e + 1], s2 = csr_src[e + 2], s3 = csr_src[e + 3];
        float a00 = alpha[(size_t)(e + 0) * 6 + h0], a01 = alpha[(size_t)(e + 0) * 6 + h1];
        float a10 = alpha[(size_t)(e + 1) * 6 + h0], a11 = alpha[(size_t)(e + 1) * 6 + h1];
        float a20 = alpha[(size_t)(e + 2) * 6 + h0], a21 = alpha[(size_t)(e + 2) * 6 + h1];
        float a30 = alpha[(size_t)(e + 3) * 6 + h0], a31 = alpha[(size_t)(e + 3) * 6 + h1];
        ushort2 u0 = *(const ushort2*)(hfeat + (size_t)s0 * 726 + q0);
        ushort2 u1 = *(const ushort2*)(hfeat + (size_t)s1 * 726 + q0);
        ushort2 u2 = *(const ushort2*)(hfeat + (size_t)s2 * 726 + q0);
        ushort2 u3 = *(const ushort2*)(hfeat + (size_t)s3 * 726 + q0);
        acc0 += a00 * bf2f(u0.x) + a10 * bf2f(u1.x) + a20 * bf2f(u2.x) + a30 * bf2f(u3.x);
        acc1 += a01 * bf2f(u0.y) + a11 * bf2f(u1.y) + a21 * bf2f(u2.y) + a31 * bf2f(u3.y);
    }
    for (; e < end; ++e) {
        int s = csr_src[e];
        float a0 = alpha[(size_t)e * 6 + h0], a1 = alpha[(size_t)e * 6 + h1];
        ushort2 u = *(const ushort2*)(hfeat + (size_t)s * 726 + q0);
        acc0 += a0 * bf2f(u.x);
        acc1 += a1 * bf2f(u.y);
    }
    if (act) { red[p0] = acc0; red[p1] = acc1; }
    __syncthreads();
    if (tid < 121) {
        float t = 0.f;
        #pragma unroll
        for (int h2 = 0; h2 < 6; ++h2) t += red[tid + 121 * h2];
        out[(size_t)n * 121 + tid] = t * (1.f / 6.f) + bias[tid];
    }
}

// ---------------------------------------------------------------- launch
extern "C" void kernel_launch(void* const* d_in, const int* in_sizes, int n_in,
                              void* d_out, int out_size, void* d_ws, size_t ws_size,
                              hipStream_t stream) {
    const float* x   = (const float*)d_in[0];
    const int*   ei  = (const int*)d_in[1];
    const float* W1  = (const float*)d_in[2];
    const float* a1s = (const float*)d_in[3];
    const float* a1d = (const float*)d_in[4];
    const float* b1  = (const float*)d_in[5];
    const float* Wl1 = (const float*)d_in[6];
    const float* bl1 = (const float*)d_in[7];
    const float* W2  = (const float*)d_in[8];
    const float* a2s = (const float*)d_in[9];
    const float* a2d = (const float*)d_in[10];
    const float* b2  = (const float*)d_in[11];
    const float* Wl2 = (const float*)d_in[12];
    const float* bl2 = (const float*)d_in[13];
    const float* W3  = (const float*)d_in[14];
    const float* a3s = (const float*)d_in[15];
    const float* a3d = (const float*)d_in[16];
    const float* b3  = (const float*)d_in[17];
    const float* Wl3 = (const float*)d_in[18];
    const float* bl3 = (const float*)d_in[19];

    float* out    = (float*)d_out;                 // [40000,121]
    float* hidden = out + (size_t)NN * 121;        // [40000,256]

    // workspace layout
    char* ws = (char*)d_ws;
    size_t off = 0;
    auto alloc = [&](size_t bytes) { size_t o = off; off = (off + bytes + 255) & ~(size_t)255; return o; };
    int*   counts    = (int*)(ws + alloc((size_t)NN * 4));
    int*   rowptr    = (int*)(ws + alloc((size_t)(NN + 1) * 4));
    int*   blocksums = (int*)(ws + alloc(256 * 4));
    int*   csr_src   = (int*)(ws + alloc((size_t)ETOT * 4));
    float* al        = (float*)(ws + alloc((size_t)NN * 6 * 4));
    float* ar        = (float*)(ws + alloc((size_t)NN * 6 * 4));
    float* alpha     = (float*)(ws + alloc((size_t)ETOT * 6 * 4));
    unsigned short* hfeatb  = (unsigned short*)(ws + alloc((size_t)NN * 726 * 2));
    unsigned short* xb      = (unsigned short*)(ws + alloc((size_t)NN * 64 * 2));
    unsigned short* h1b     = (unsigned short*)(ws + alloc((size_t)NN * 256 * 2));
    unsigned short* hiddenb = (unsigned short*)(ws + alloc((size_t)NN * 256 * 2));
    unsigned short* w1t     = (unsigned short*)(ws + alloc((size_t)256 * 64 * 2));
    unsigned short* wl1t    = (unsigned short*)(ws + alloc((size_t)256 * 64 * 2));
    unsigned short* w2t     = (unsigned short*)(ws + alloc((size_t)256 * 256 * 2));
    unsigned short* wl2t    = (unsigned short*)(ws + alloc((size_t)256 * 256 * 2));
    unsigned short* w3t     = (unsigned short*)(ws + alloc((size_t)726 * 256 * 2));
    unsigned short* wl3t    = (unsigned short*)(ws + alloc((size_t)121 * 256 * 2));

    const int eblocks = (ETOT + 255) / 256;
    const int ablocks = (NN + 3) / 4;
    const int mg = (NN + 127) / 128;   // 313

    // ---- prep: bf16 conversions (cheap, deterministic)
    xprep_k<<<(NN * 64 + 255) / 256, 256, 0, stream>>>(x, xb);
    wprep_k<<<256, 64, 0, stream>>>(W1,  w1t,  50, 256, 64);
    wprep_k<<<256, 64, 0, stream>>>(Wl1, wl1t, 50, 256, 64);
    wprep_k<<<256, 256, 0, stream>>>(W2,  w2t,  256, 256, 256);
    wprep_k<<<256, 256, 0, stream>>>(Wl2, wl2t, 256, 256, 256);
    wprep_k<<<726, 256, 0, stream>>>(W3,  w3t,  256, 726, 256);
    wprep_k<<<121, 256, 0, stream>>>(Wl3, wl3t, 256, 121, 256);

    // ---- CSR build (same for all layers)
    hipMemsetAsync(counts, 0, (size_t)NN * 4, stream);
    count_k<<<eblocks, 256, 0, stream>>>(ei, counts);
    scan_k<<<NBLK, 256, 0, stream>>>(counts, rowptr, blocksums, NN);
    scan_k<<<1, 256, 0, stream>>>(blocksums, blocksums, nullptr, NBLK);
    add_off_k<<<NBLK, 256, 0, stream>>>(rowptr, blocksums);
    hipMemsetAsync(counts, 0, (size_t)NN * 4, stream);  // reuse as cursor
    scatter_k<<<eblocks, 256, 0, stream>>>(ei, rowptr, counts, csr_src);

    // ---- Layer 1: in=xb[N,64], out=h1b[N,256] bf16
    gemm_bf16_k<3><<<dim3(2, mg), 256, 0, stream>>>(xb, w1t, nullptr, nullptr, hfeatb, NN, 256, 64);
    alar_k<<<dim3(4, NN), 64, 0, stream>>>(hfeatb, a1s, a1d, al, ar, 4, 64);
    attn_alpha_k<4, 4, 2><<<ablocks, 256, 0, stream>>>(rowptr, csr_src, al, ar, alpha);
    gather_concat_k<true><<<NN / 2, 256, 0, stream>>>(rowptr, csr_src, hfeatb, alpha, b1, nullptr, h1b);
    gemm_bf16_k<1><<<dim3(2, mg), 256, 0, stream>>>(xb, wl1t, bl1, nullptr, h1b, NN, 256, 64);

    // ---- Layer 2: in=h1b, out=hidden (d_out f32) + hiddenb bf16
    gemm_bf16_k<3><<<dim3(2, mg), 256, 0, stream>>>(h1b, w2t, nullptr, nullptr, hfeatb, NN, 256, 256);
    alar_k<<<dim3(4, NN), 64, 0, stream>>>(hfeatb, a2s, a2d, al, ar, 4, 64);
    attn_alpha_k<4, 4, 2><<<ablocks, 256, 0, stream>>>(rowptr, csr_src, al, ar, alpha);
    gather_concat_k<false><<<NN / 2, 256, 0, stream>>>(rowptr, csr_src, hfeatb, alpha, b2, hidden, nullptr);
    gemm_bf16_k<4><<<dim3(2, mg), 256, 0, stream>>>(h1b, wl2t, bl2, hidden, hiddenb, NN, 256, 256);

    // ---- Layer 3: in=hiddenb, out=out[N,121] (mean over 6 heads)
    gemm_bf16_k<3><<<dim3(6, mg), 256, 0, stream>>>(hiddenb, w3t, nullptr, nullptr, hfeatb, NN, 726, 256);
    alar_k<<<dim3(6, NN), 64, 0, stream>>>(hfeatb, a3s, a3d, al, ar, 6, 121);
    attn_alpha_k<6, 8, 3><<<ablocks, 256, 0, stream>>>(rowptr, csr_src, al, ar, alpha);
    gather_mean_k<<<NN, 384, 0, stream>>>(rowptr, csr_src, hfeatb, alpha, b3, out);
    gemm_bf16_k<2><<<dim3(1, mg), 256, 0, stream>>>(hiddenb, wl3t, bl3, out, nullptr, NN, 121, 256);
}